// Round 1
// baseline (23442.297 us; speedup 1.0000x reference)
//
#include <hip/hip_runtime.h>
#include <math.h>

// Model dims
#define BATCH 128
#define DMODEL 512
#define NHEAD 8
#define NLAYER 6
#define SEQ 200
#define LATDIM 256
#define OUTDIM 6
#define DKH 64
#define DFF 2048
#define ROWS (BATCH * SEQ)   // 25600

__device__ __forceinline__ float gelu_f(float v) {
    return 0.5f * v * (1.0f + erff(v * 0.70710678118654752f));
}

enum { EP_BIAS = 0, EP_GELU = 1, EP_GELU_PE = 2, EP_RESID = 3 };

// C[M,N] = epilogue(A[M,K] @ B[K,N] + bias[N]); M,N multiples of 64, K multiple of 16.
__global__ __launch_bounds__(256) void gemm_kernel(
    const float* __restrict__ A, const float* __restrict__ B,
    const float* __restrict__ bias, float* __restrict__ C,
    int M, int N, int K, int mode)
{
    __shared__ float As[16][65];
    __shared__ float Bs[16][68];
    const int tid = threadIdx.x;
    const int bn = blockIdx.x, bm = blockIdx.y;
    const int row0 = bm * 64, col0 = bn * 64;
    const int ty = tid >> 4, tx = tid & 15;
    const int a_row = tid >> 2, a_col = (tid & 3) << 2;
    const int b_row = tid >> 4, b_col = (tid & 15) << 2;
    const float* Ap = A + (size_t)(row0 + a_row) * K + a_col;
    const float* Bp = B + (size_t)b_row * N + col0 + b_col;
    float acc[4][4] = {};
    for (int k0 = 0; k0 < K; k0 += 16) {
        float4 av = *(const float4*)(Ap + k0);
        As[a_col + 0][a_row] = av.x;
        As[a_col + 1][a_row] = av.y;
        As[a_col + 2][a_row] = av.z;
        As[a_col + 3][a_row] = av.w;
        float4 bv = *(const float4*)(Bp + (size_t)k0 * N);
        *(float4*)&Bs[b_row][b_col] = bv;
        __syncthreads();
        #pragma unroll
        for (int kk = 0; kk < 16; ++kk) {
            float a[4], b[4];
            #pragma unroll
            for (int i = 0; i < 4; ++i) a[i] = As[kk][ty * 4 + i];
            #pragma unroll
            for (int j = 0; j < 4; ++j) b[j] = Bs[kk][tx * 4 + j];
            #pragma unroll
            for (int i = 0; i < 4; ++i)
                #pragma unroll
                for (int j = 0; j < 4; ++j)
                    acc[i][j] = fmaf(a[i], b[j], acc[i][j]);
        }
        __syncthreads();
    }
    #pragma unroll
    for (int i = 0; i < 4; ++i) {
        const int r = row0 + ty * 4 + i;
        #pragma unroll
        for (int j = 0; j < 4; ++j) {
            const int c = col0 + tx * 4 + j;
            float v = acc[i][j] + bias[c];
            if (mode == EP_GELU) {
                v = gelu_f(v);
            } else if (mode == EP_GELU_PE) {
                v = gelu_f(v);
                // x += pe[s,d];  col c = s*512 + d
                int s = c >> 9, d = c & 511;
                float ang = (float)s * expf((float)(d & ~1) * (-9.2103403719761836f / 512.0f));
                v += (d & 1) ? cosf(ang) : sinf(ang);
            } else if (mode == EP_RESID) {
                v += C[(size_t)r * N + c];   // residual accumulate in place
            }
            C[(size_t)r * N + c] = v;
        }
    }
}

// Fused attention for one (b, h, i): scores -> softmax -> ctx.
// q,k,v layout: [B*S, 512] with head h at cols h*64..h*64+63.
__global__ __launch_bounds__(256) void attn_kernel(
    const float* __restrict__ q, const float* __restrict__ k,
    const float* __restrict__ v, const float* __restrict__ tb,
    float* __restrict__ ctx)
{
    const int i = blockIdx.x, h = blockIdx.y, b = blockIdx.z;
    const int tid = threadIdx.x;
    __shared__ float qs[64];
    __shared__ float sc[256];
    __shared__ float red[256];
    __shared__ float cred[4][64];
    if (tid < 64) qs[tid] = q[(size_t)(b * SEQ + i) * DMODEL + h * 64 + tid];
    __syncthreads();
    float sv = -INFINITY;
    if (tid < SEQ) {
        const float* kr = k + (size_t)(b * SEQ + tid) * DMODEL + h * 64;
        float a = 0.f;
        #pragma unroll 16
        for (int d = 0; d < 64; ++d) a = fmaf(qs[d], kr[d], a);
        sv = a * 0.125f + tb[((h * SEQ) + i) * SEQ + tid];
    }
    sc[tid] = sv;
    red[tid] = sv;
    __syncthreads();
    for (int s = 128; s > 0; s >>= 1) {
        if (tid < s) red[tid] = fmaxf(red[tid], red[tid + s]);
        __syncthreads();
    }
    const float m = red[0];
    __syncthreads();
    float e = 0.f;
    if (tid < SEQ) { e = expf(sc[tid] - m); sc[tid] = e; }
    red[tid] = e;
    __syncthreads();
    for (int s = 128; s > 0; s >>= 1) {
        if (tid < s) red[tid] += red[tid + s];
        __syncthreads();
    }
    const float inv = 1.0f / red[0];
    // ctx[dk] = inv * sum_j sc[j] * v[b,j,h,dk]; 4 partials of 50 j's each
    const int dk = tid & 63, part = tid >> 6;
    const float* vb = v + (size_t)b * SEQ * DMODEL + h * 64 + dk;
    float p = 0.f;
    for (int j = part * 50; j < part * 50 + 50; ++j)
        p = fmaf(sc[j], vb[(size_t)j * DMODEL], p);
    cred[part][dk] = p;
    __syncthreads();
    if (tid < 64)
        ctx[(size_t)(b * SEQ + i) * DMODEL + h * 64 + tid] =
            (cred[0][tid] + cred[1][tid] + cred[2][tid] + cred[3][tid]) * inv;
}

// In-place LayerNorm over rows of 512, eps=1e-5
__global__ __launch_bounds__(256) void ln_kernel(
    float* __restrict__ x, const float* __restrict__ g, const float* __restrict__ bb)
{
    const int tid = threadIdx.x;
    float* xr = x + (size_t)blockIdx.x * DMODEL;
    float v0 = xr[tid], v1 = xr[tid + 256];
    __shared__ float red[256];
    red[tid] = v0 + v1;
    __syncthreads();
    for (int s = 128; s > 0; s >>= 1) { if (tid < s) red[tid] += red[tid + s]; __syncthreads(); }
    const float mu = red[0] * (1.0f / 512.0f);
    __syncthreads();
    const float d0 = v0 - mu, d1 = v1 - mu;
    red[tid] = d0 * d0 + d1 * d1;
    __syncthreads();
    for (int s = 128; s > 0; s >>= 1) { if (tid < s) red[tid] += red[tid + s]; __syncthreads(); }
    const float rstd = rsqrtf(red[0] * (1.0f / 512.0f) + 1e-5f);
    xr[tid]       = d0 * rstd * g[tid] + bb[tid];
    xr[tid + 256] = d1 * rstd * g[tid + 256] + bb[tid + 256];
}

__global__ __launch_bounds__(256) void concat_z_kernel(
    const float* __restrict__ zs, const float* __restrict__ zk, float* __restrict__ z)
{
    const int b = blockIdx.x, t = threadIdx.x;
    z[b * 256 + t] = (t < 128) ? zs[b * 128 + t] : zk[b * 128 + t - 128];
}

// trajectory = t1[25600,256] @ Wp2[256,6] + bp2
__global__ __launch_bounds__(64) void traj_head_kernel(
    const float* __restrict__ t1, const float* __restrict__ Wp2,
    const float* __restrict__ bp2, float* __restrict__ out)
{
    const int r = blockIdx.x, t = threadIdx.x;
    __shared__ float red[6][64];
    float p[6] = {};
    const float* tr = t1 + (size_t)r * 256;
    for (int kk = t; kk < 256; kk += 64) {
        float tv = tr[kk];
        #pragma unroll
        for (int c = 0; c < 6; ++c) p[c] = fmaf(tv, Wp2[kk * 6 + c], p[c]);
    }
    #pragma unroll
    for (int c = 0; c < 6; ++c) red[c][t] = p[c];
    __syncthreads();
    if (t < 6) {
        float a = 0.f;
        for (int j = 0; j < 64; ++j) a += red[t][j];
        out[(size_t)r * 6 + t] = a + bp2[t];
    }
}

// signatures = gelu(z @ Ws1 + bs1) @ Ws2 + bs2, per batch row
__global__ __launch_bounds__(256) void sig_head_kernel(
    const float* __restrict__ zs, const float* __restrict__ zk,
    const float* __restrict__ Ws1, const float* __restrict__ bs1,
    const float* __restrict__ Ws2, const float* __restrict__ bs2,
    float* __restrict__ out)
{
    const int b = blockIdx.x, t = threadIdx.x;
    __shared__ float zrow[256];
    __shared__ float h1[256];
    zrow[t] = (t < 128) ? zs[b * 128 + t] : zk[b * 128 + t - 128];
    __syncthreads();
    float acc = bs1[t];
    for (int kk = 0; kk < 256; ++kk) acc = fmaf(zrow[kk], Ws1[kk * 256 + t], acc);
    h1[t] = gelu_f(acc);
    __syncthreads();
    if (t < 5) {
        float a = bs2[t];
        for (int kk = 0; kk < 256; ++kk) a = fmaf(h1[kk], Ws2[kk * 5 + t], a);
        out[b * 5 + t] = a;
    }
}

extern "C" void kernel_launch(void* const* d_in, const int* in_sizes, int n_in,
                              void* d_out, int out_size, void* d_ws, size_t ws_size,
                              hipStream_t stream) {
    const float* z_style   = (const float*)d_in[0];
    const float* z_skill   = (const float*)d_in[1];
    const float* W_lat     = (const float*)d_in[2];
    const float* b_lat     = (const float*)d_in[3];
    const float* temp_bias = (const float*)d_in[4];
    const float* Wq  = (const float*)d_in[5];
    const float* bq  = (const float*)d_in[6];
    const float* Wk  = (const float*)d_in[7];
    const float* bk  = (const float*)d_in[8];
    const float* Wv  = (const float*)d_in[9];
    const float* bv  = (const float*)d_in[10];
    const float* Wo  = (const float*)d_in[11];
    const float* bo  = (const float*)d_in[12];
    const float* g1  = (const float*)d_in[13];
    const float* be1 = (const float*)d_in[14];
    const float* g2  = (const float*)d_in[15];
    const float* be2 = (const float*)d_in[16];
    const float* W1  = (const float*)d_in[17];
    const float* bf1 = (const float*)d_in[18];
    const float* W2  = (const float*)d_in[19];
    const float* bf2 = (const float*)d_in[20];
    const float* Wp1 = (const float*)d_in[21];
    const float* bp1 = (const float*)d_in[22];
    const float* Wp2 = (const float*)d_in[23];
    const float* bp2 = (const float*)d_in[24];
    const float* Ws1 = (const float*)d_in[25];
    const float* bs1 = (const float*)d_in[26];
    const float* Ws2 = (const float*)d_in[27];
    const float* bs2 = (const float*)d_in[28];
    float* out = (float*)d_out;

    const size_t NBUF = (size_t)ROWS * DMODEL;   // 13,107,200 floats
    float* x  = (float*)d_ws;
    float* s0 = x  + NBUF;
    float* s1 = s0 + NBUF;
    float* s2 = s1 + NBUF;
    float* s3 = s2 + NBUF;          // s0..s3 contiguous: doubles as ff1 [25600,2048]
    float* zb = s3 + NBUF;          // [128,256]

    // z = concat(z_style, z_skill)
    concat_z_kernel<<<BATCH, 256, 0, stream>>>(z_style, z_skill, zb);

    // x = gelu(z @ W_lat + b_lat) + pe   [128, 102400] -> [B,S,D]
    gemm_kernel<<<dim3(102400 / 64, BATCH / 64), 256, 0, stream>>>(
        zb, W_lat, b_lat, x, BATCH, DMODEL * SEQ, LATDIM, EP_GELU_PE);

    const dim3 gSq(DMODEL / 64, ROWS / 64);      // (8, 400)
    const dim3 gFF(DFF / 64, ROWS / 64);         // (32, 400)
    for (int l = 0; l < NLAYER; ++l) {
        const size_t wOff = (size_t)l * DMODEL * DMODEL;
        const size_t fOff = (size_t)l * DMODEL * DFF;
        // q,k,v
        gemm_kernel<<<gSq, 256, 0, stream>>>(x, Wq + wOff, bq + l * DMODEL, s0,
                                             ROWS, DMODEL, DMODEL, EP_BIAS);
        gemm_kernel<<<gSq, 256, 0, stream>>>(x, Wk + wOff, bk + l * DMODEL, s1,
                                             ROWS, DMODEL, DMODEL, EP_BIAS);
        gemm_kernel<<<gSq, 256, 0, stream>>>(x, Wv + wOff, bv + l * DMODEL, s2,
                                             ROWS, DMODEL, DMODEL, EP_BIAS);
        // attention -> ctx (s3)
        attn_kernel<<<dim3(SEQ, NHEAD, BATCH), 256, 0, stream>>>(s0, s1, s2, temp_bias, s3);
        // x += ctx @ Wo + bo ; LN1
        gemm_kernel<<<gSq, 256, 0, stream>>>(s3, Wo + wOff, bo + l * DMODEL, x,
                                             ROWS, DMODEL, DMODEL, EP_RESID);
        ln_kernel<<<ROWS, 256, 0, stream>>>(x, g1 + l * DMODEL, be1 + l * DMODEL);
        // ff1 = gelu(x @ W1 + bf1)  [25600,2048] spans s0..s3
        gemm_kernel<<<gFF, 256, 0, stream>>>(x, W1 + fOff, bf1 + l * DFF, s0,
                                             ROWS, DFF, DMODEL, EP_GELU);
        // x += ff1 @ W2 + bf2 ; LN2
        gemm_kernel<<<gSq, 256, 0, stream>>>(s0, W2 + fOff, bf2 + l * DMODEL, x,
                                             ROWS, DMODEL, DFF, EP_RESID);
        ln_kernel<<<ROWS, 256, 0, stream>>>(x, g2 + l * DMODEL, be2 + l * DMODEL);
    }

    // trajectory head: t1 = gelu(x @ Wp1 + bp1) [25600,256] -> s0
    gemm_kernel<<<dim3(256 / 64, ROWS / 64), 256, 0, stream>>>(
        x, Wp1, bp1, s0, ROWS, 256, DMODEL, EP_GELU);
    traj_head_kernel<<<ROWS, 64, 0, stream>>>(s0, Wp2, bp2, out);

    // signatures head
    sig_head_kernel<<<BATCH, 256, 0, stream>>>(z_style, z_skill, Ws1, bs1, Ws2, bs2,
                                               out + (size_t)ROWS * OUTDIM);
}

// Round 2
// 17411.845 us; speedup vs baseline: 1.3463x; 1.3463x over previous
//
#include <hip/hip_runtime.h>
#include <math.h>

// Model dims
#define BATCH 128
#define DMODEL 512
#define NHEAD 8
#define NLAYER 6
#define SEQ 200
#define LATDIM 256
#define OUTDIM 6
#define DKH 64
#define DFF 2048
#define ROWS (BATCH * SEQ)   // 25600

__device__ __forceinline__ float gelu_f(float v) {
    return 0.5f * v * (1.0f + erff(v * 0.70710678118654752f));
}

enum { EP_BIAS = 0, EP_GELU = 1, EP_GELU_PE = 2, EP_RESID = 3 };

// C[M,N] = epilogue(A[M,K] @ B[K,N] + bias[N]); M,N multiples of 64, K multiple of 16.
__global__ __launch_bounds__(256) void gemm_kernel(
    const float* __restrict__ A, const float* __restrict__ B,
    const float* __restrict__ bias, float* __restrict__ C,
    int M, int N, int K, int mode)
{
    __shared__ float As[16][65];
    __shared__ float Bs[16][68];
    const int tid = threadIdx.x;
    const int bn = blockIdx.x, bm = blockIdx.y;
    const int row0 = bm * 64, col0 = bn * 64;
    const int ty = tid >> 4, tx = tid & 15;
    const int a_row = tid >> 2, a_col = (tid & 3) << 2;
    const int b_row = tid >> 4, b_col = (tid & 15) << 2;
    const float* Ap = A + (size_t)(row0 + a_row) * K + a_col;
    const float* Bp = B + (size_t)b_row * N + col0 + b_col;
    float acc[4][4] = {};
    for (int k0 = 0; k0 < K; k0 += 16) {
        float4 av = *(const float4*)(Ap + k0);
        As[a_col + 0][a_row] = av.x;
        As[a_col + 1][a_row] = av.y;
        As[a_col + 2][a_row] = av.z;
        As[a_col + 3][a_row] = av.w;
        float4 bv = *(const float4*)(Bp + (size_t)k0 * N);
        *(float4*)&Bs[b_row][b_col] = bv;
        __syncthreads();
        #pragma unroll
        for (int kk = 0; kk < 16; ++kk) {
            float a[4], b[4];
            #pragma unroll
            for (int i = 0; i < 4; ++i) a[i] = As[kk][ty * 4 + i];
            #pragma unroll
            for (int j = 0; j < 4; ++j) b[j] = Bs[kk][tx * 4 + j];
            #pragma unroll
            for (int i = 0; i < 4; ++i)
                #pragma unroll
                for (int j = 0; j < 4; ++j)
                    acc[i][j] = fmaf(a[i], b[j], acc[i][j]);
        }
        __syncthreads();
    }
    #pragma unroll
    for (int i = 0; i < 4; ++i) {
        const int r = row0 + ty * 4 + i;
        #pragma unroll
        for (int j = 0; j < 4; ++j) {
            const int c = col0 + tx * 4 + j;
            float v = acc[i][j] + bias[c];
            if (mode == EP_GELU) {
                v = gelu_f(v);
            } else if (mode == EP_GELU_PE) {
                v = gelu_f(v);
                // x += pe[s,d];  col c = s*512 + d
                int s = c >> 9, d = c & 511;
                float ang = (float)s * expf((float)(d & ~1) * (-9.2103403719761836f / 512.0f));
                v += (d & 1) ? cosf(ang) : sinf(ang);
            } else if (mode == EP_RESID) {
                v += C[(size_t)r * N + c];   // residual accumulate in place
            }
            C[(size_t)r * N + c] = v;
        }
    }
}

// Fused attention, one block per (b,h). 256 threads = 4 waves.
// Per block-iteration: 32 queries (8 per wave). Two-pass softmax.
// LDS: Ks (K/V tile, odd-padded), sbuf (scores, odd-padded), qT/pT (32B rows
// for aligned float4 broadcast reads).  Total 61,824 B < 64 KB.
__global__ __launch_bounds__(256) void attn_kernel(
    const float* __restrict__ q, const float* __restrict__ k,
    const float* __restrict__ v, const float* __restrict__ tb,
    float* __restrict__ ctx)
{
    const int h = blockIdx.x, b = blockIdx.y;
    const int tid = threadIdx.x;
    const int w = tid >> 6, lane = tid & 63;

    __shared__ float Ks[64][65];        // K or V tile (16,640 B)
    __shared__ float sbuf[4][200][9];   // scores per wave (28,800 B)
    __shared__ float qT[4][64][8];      // q transposed per wave (8,192 B)
    __shared__ float pT[4][64][8];      // softmaxed p tile per wave (8,192 B)

    const size_t bhq = (size_t)b * SEQ * DMODEL + h * 64;

    for (int ci = 0; ci < 7; ++ci) {                 // 7*32 = 224 >= 200
        const int i_base = ci * 32 + w * 8;
        const bool active = (i_base < SEQ);

        // --- load 8 q rows into qT[w][d][qi] ---
        if (active) {
            #pragma unroll
            for (int qi = 0; qi < 8; ++qi)
                qT[w][lane][qi] = q[bhq + (size_t)(i_base + qi) * DMODEL + lane];
        }

        // --- phase 1: scores ---
        for (int t = 0; t < 4; ++t) {
            const int j0 = t * 64;
            const int jn = (SEQ - j0 < 64) ? (SEQ - j0) : 64;
            __syncthreads();
            for (int g = tid; g < jn * 16; g += 256) {
                const int row = g >> 4, c4 = (g & 15) << 2;
                float4 kv = *(const float4*)(k + bhq + (size_t)(j0 + row) * DMODEL + c4);
                Ks[row][c4 + 0] = kv.x; Ks[row][c4 + 1] = kv.y;
                Ks[row][c4 + 2] = kv.z; Ks[row][c4 + 3] = kv.w;
            }
            __syncthreads();
            if (active && lane < jn) {
                float acc[8] = {};
                #pragma unroll 8
                for (int d = 0; d < 64; ++d) {
                    const float kv = Ks[lane][d];
                    const float4 qa = *(const float4*)&qT[w][d][0];
                    const float4 qb = *(const float4*)&qT[w][d][4];
                    acc[0] = fmaf(kv, qa.x, acc[0]); acc[1] = fmaf(kv, qa.y, acc[1]);
                    acc[2] = fmaf(kv, qa.z, acc[2]); acc[3] = fmaf(kv, qa.w, acc[3]);
                    acc[4] = fmaf(kv, qb.x, acc[4]); acc[5] = fmaf(kv, qb.y, acc[5]);
                    acc[6] = fmaf(kv, qb.z, acc[6]); acc[7] = fmaf(kv, qb.w, acc[7]);
                }
                const int j = j0 + lane;
                #pragma unroll
                for (int qi = 0; qi < 8; ++qi) {
                    const float bias = tb[((h * SEQ) + i_base + qi) * SEQ + j];
                    sbuf[w][j][qi] = acc[qi] * 0.125f + bias;
                }
            }
        }

        // --- softmax over sbuf[w] (per wave, no block barrier needed) ---
        float cacc[8] = {};
        if (active) {
            float sv[8][4];
            #pragma unroll
            for (int jj = 0; jj < 4; ++jj) {
                const int j = jj * 64 + lane;
                #pragma unroll
                for (int qi = 0; qi < 8; ++qi)
                    sv[qi][jj] = (j < SEQ) ? sbuf[w][j][qi] : -INFINITY;
            }
            #pragma unroll
            for (int qi = 0; qi < 8; ++qi) {
                float m = fmaxf(fmaxf(sv[qi][0], sv[qi][1]), fmaxf(sv[qi][2], sv[qi][3]));
                #pragma unroll
                for (int off = 32; off > 0; off >>= 1)
                    m = fmaxf(m, __shfl_xor(m, off, 64));
                float e[4], s = 0.f;
                #pragma unroll
                for (int jj = 0; jj < 4; ++jj) { e[jj] = __expf(sv[qi][jj] - m); s += e[jj]; }
                #pragma unroll
                for (int off = 32; off > 0; off >>= 1)
                    s += __shfl_xor(s, off, 64);
                const float inv = 1.0f / s;
                #pragma unroll
                for (int jj = 0; jj < 4; ++jj) {
                    const int j = jj * 64 + lane;
                    if (j < SEQ) sbuf[w][j][qi] = e[jj] * inv;
                }
            }
        }

        // --- phase 2: ctx = P @ V ---
        for (int t = 0; t < 4; ++t) {
            const int j0 = t * 64;
            const int jn = (SEQ - j0 < 64) ? (SEQ - j0) : 64;
            __syncthreads();
            for (int g = tid; g < jn * 16; g += 256) {
                const int row = g >> 4, c4 = (g & 15) << 2;
                float4 vv = *(const float4*)(v + bhq + (size_t)(j0 + row) * DMODEL + c4);
                Ks[row][c4 + 0] = vv.x; Ks[row][c4 + 1] = vv.y;
                Ks[row][c4 + 2] = vv.z; Ks[row][c4 + 3] = vv.w;
            }
            __syncthreads();
            if (active) {
                if (lane < jn) {
                    #pragma unroll
                    for (int qi = 0; qi < 8; ++qi)
                        pT[w][lane][qi] = sbuf[w][j0 + lane][qi];
                }
                // per-wave LDS write->read, wave-coherent (compiler inserts lgkmcnt)
                for (int jj = 0; jj < jn; ++jj) {
                    const float vv = Ks[jj][lane];
                    const float4 pa = *(const float4*)&pT[w][jj][0];
                    const float4 pb = *(const float4*)&pT[w][jj][4];
                    cacc[0] = fmaf(vv, pa.x, cacc[0]); cacc[1] = fmaf(vv, pa.y, cacc[1]);
                    cacc[2] = fmaf(vv, pa.z, cacc[2]); cacc[3] = fmaf(vv, pa.w, cacc[3]);
                    cacc[4] = fmaf(vv, pb.x, cacc[4]); cacc[5] = fmaf(vv, pb.y, cacc[5]);
                    cacc[6] = fmaf(vv, pb.z, cacc[6]); cacc[7] = fmaf(vv, pb.w, cacc[7]);
                }
            }
        }

        if (active) {
            #pragma unroll
            for (int qi = 0; qi < 8; ++qi)
                ctx[bhq + (size_t)(i_base + qi) * DMODEL + lane] = cacc[qi];
        }
    }
}

// In-place LayerNorm over rows of 512, eps=1e-5
__global__ __launch_bounds__(256) void ln_kernel(
    float* __restrict__ x, const float* __restrict__ g, const float* __restrict__ bb)
{
    const int tid = threadIdx.x;
    float* xr = x + (size_t)blockIdx.x * DMODEL;
    float v0 = xr[tid], v1 = xr[tid + 256];
    __shared__ float red[256];
    red[tid] = v0 + v1;
    __syncthreads();
    for (int s = 128; s > 0; s >>= 1) { if (tid < s) red[tid] += red[tid + s]; __syncthreads(); }
    const float mu = red[0] * (1.0f / 512.0f);
    __syncthreads();
    const float d0 = v0 - mu, d1 = v1 - mu;
    red[tid] = d0 * d0 + d1 * d1;
    __syncthreads();
    for (int s = 128; s > 0; s >>= 1) { if (tid < s) red[tid] += red[tid + s]; __syncthreads(); }
    const float rstd = rsqrtf(red[0] * (1.0f / 512.0f) + 1e-5f);
    xr[tid]       = d0 * rstd * g[tid] + bb[tid];
    xr[tid + 256] = d1 * rstd * g[tid + 256] + bb[tid + 256];
}

__global__ __launch_bounds__(256) void concat_z_kernel(
    const float* __restrict__ zs, const float* __restrict__ zk, float* __restrict__ z)
{
    const int b = blockIdx.x, t = threadIdx.x;
    z[b * 256 + t] = (t < 128) ? zs[b * 128 + t] : zk[b * 128 + t - 128];
}

// trajectory = t1[25600,256] @ Wp2[256,6] + bp2
__global__ __launch_bounds__(64) void traj_head_kernel(
    const float* __restrict__ t1, const float* __restrict__ Wp2,
    const float* __restrict__ bp2, float* __restrict__ out)
{
    const int r = blockIdx.x, t = threadIdx.x;
    __shared__ float red[6][64];
    float p[6] = {};
    const float* tr = t1 + (size_t)r * 256;
    for (int kk = t; kk < 256; kk += 64) {
        float tv = tr[kk];
        #pragma unroll
        for (int c = 0; c < 6; ++c) p[c] = fmaf(tv, Wp2[kk * 6 + c], p[c]);
    }
    #pragma unroll
    for (int c = 0; c < 6; ++c) red[c][t] = p[c];
    __syncthreads();
    if (t < 6) {
        float a = 0.f;
        for (int j = 0; j < 64; ++j) a += red[t][j];
        out[(size_t)r * 6 + t] = a + bp2[t];
    }
}

// signatures = gelu(z @ Ws1 + bs1) @ Ws2 + bs2, per batch row
__global__ __launch_bounds__(256) void sig_head_kernel(
    const float* __restrict__ zs, const float* __restrict__ zk,
    const float* __restrict__ Ws1, const float* __restrict__ bs1,
    const float* __restrict__ Ws2, const float* __restrict__ bs2,
    float* __restrict__ out)
{
    const int b = blockIdx.x, t = threadIdx.x;
    __shared__ float zrow[256];
    __shared__ float h1[256];
    zrow[t] = (t < 128) ? zs[b * 128 + t] : zk[b * 128 + t - 128];
    __syncthreads();
    float acc = bs1[t];
    for (int kk = 0; kk < 256; ++kk) acc = fmaf(zrow[kk], Ws1[kk * 256 + t], acc);
    h1[t] = gelu_f(acc);
    __syncthreads();
    if (t < 5) {
        float a = bs2[t];
        for (int kk = 0; kk < 256; ++kk) a = fmaf(h1[kk], Ws2[kk * 5 + t], a);
        out[b * 5 + t] = a;
    }
}

extern "C" void kernel_launch(void* const* d_in, const int* in_sizes, int n_in,
                              void* d_out, int out_size, void* d_ws, size_t ws_size,
                              hipStream_t stream) {
    const float* z_style   = (const float*)d_in[0];
    const float* z_skill   = (const float*)d_in[1];
    const float* W_lat     = (const float*)d_in[2];
    const float* b_lat     = (const float*)d_in[3];
    const float* temp_bias = (const float*)d_in[4];
    const float* Wq  = (const float*)d_in[5];
    const float* bq  = (const float*)d_in[6];
    const float* Wk  = (const float*)d_in[7];
    const float* bk  = (const float*)d_in[8];
    const float* Wv  = (const float*)d_in[9];
    const float* bv  = (const float*)d_in[10];
    const float* Wo  = (const float*)d_in[11];
    const float* bo  = (const float*)d_in[12];
    const float* g1  = (const float*)d_in[13];
    const float* be1 = (const float*)d_in[14];
    const float* g2  = (const float*)d_in[15];
    const float* be2 = (const float*)d_in[16];
    const float* W1  = (const float*)d_in[17];
    const float* bf1 = (const float*)d_in[18];
    const float* W2  = (const float*)d_in[19];
    const float* bf2 = (const float*)d_in[20];
    const float* Wp1 = (const float*)d_in[21];
    const float* bp1 = (const float*)d_in[22];
    const float* Wp2 = (const float*)d_in[23];
    const float* bp2 = (const float*)d_in[24];
    const float* Ws1 = (const float*)d_in[25];
    const float* bs1 = (const float*)d_in[26];
    const float* Ws2 = (const float*)d_in[27];
    const float* bs2 = (const float*)d_in[28];
    float* out = (float*)d_out;

    const size_t NBUF = (size_t)ROWS * DMODEL;   // 13,107,200 floats
    float* x  = (float*)d_ws;
    float* s0 = x  + NBUF;
    float* s1 = s0 + NBUF;
    float* s2 = s1 + NBUF;
    float* s3 = s2 + NBUF;          // s0..s3 contiguous: doubles as ff1 [25600,2048]
    float* zb = s3 + NBUF;          // [128,256]

    // z = concat(z_style, z_skill)
    concat_z_kernel<<<BATCH, 256, 0, stream>>>(z_style, z_skill, zb);

    // x = gelu(z @ W_lat + b_lat) + pe   [128, 102400] -> [B,S,D]
    gemm_kernel<<<dim3(102400 / 64, BATCH / 64), 256, 0, stream>>>(
        zb, W_lat, b_lat, x, BATCH, DMODEL * SEQ, LATDIM, EP_GELU_PE);

    const dim3 gSq(DMODEL / 64, ROWS / 64);      // (8, 400)
    const dim3 gFF(DFF / 64, ROWS / 64);         // (32, 400)
    for (int l = 0; l < NLAYER; ++l) {
        const size_t wOff = (size_t)l * DMODEL * DMODEL;
        const size_t fOff = (size_t)l * DMODEL * DFF;
        // q,k,v
        gemm_kernel<<<gSq, 256, 0, stream>>>(x, Wq + wOff, bq + l * DMODEL, s0,
                                             ROWS, DMODEL, DMODEL, EP_BIAS);
        gemm_kernel<<<gSq, 256, 0, stream>>>(x, Wk + wOff, bk + l * DMODEL, s1,
                                             ROWS, DMODEL, DMODEL, EP_BIAS);
        gemm_kernel<<<gSq, 256, 0, stream>>>(x, Wv + wOff, bv + l * DMODEL, s2,
                                             ROWS, DMODEL, DMODEL, EP_BIAS);
        // attention -> ctx (s3); one block per (b,h)
        attn_kernel<<<dim3(NHEAD, BATCH), 256, 0, stream>>>(s0, s1, s2, temp_bias, s3);
        // x += ctx @ Wo + bo ; LN1
        gemm_kernel<<<gSq, 256, 0, stream>>>(s3, Wo + wOff, bo + l * DMODEL, x,
                                             ROWS, DMODEL, DMODEL, EP_RESID);
        ln_kernel<<<ROWS, 256, 0, stream>>>(x, g1 + l * DMODEL, be1 + l * DMODEL);
        // ff1 = gelu(x @ W1 + bf1)  [25600,2048] spans s0..s3
        gemm_kernel<<<gFF, 256, 0, stream>>>(x, W1 + fOff, bf1 + l * DFF, s0,
                                             ROWS, DFF, DMODEL, EP_GELU);
        // x += ff1 @ W2 + bf2 ; LN2
        gemm_kernel<<<gSq, 256, 0, stream>>>(s0, W2 + fOff, bf2 + l * DMODEL, x,
                                             ROWS, DMODEL, DFF, EP_RESID);
        ln_kernel<<<ROWS, 256, 0, stream>>>(x, g2 + l * DMODEL, be2 + l * DMODEL);
    }

    // trajectory head: t1 = gelu(x @ Wp1 + bp1) [25600,256] -> s0
    gemm_kernel<<<dim3(256 / 64, ROWS / 64), 256, 0, stream>>>(
        x, Wp1, bp1, s0, ROWS, 256, DMODEL, EP_GELU);
    traj_head_kernel<<<ROWS, 64, 0, stream>>>(s0, Wp2, bp2, out);

    // signatures head
    sig_head_kernel<<<BATCH, 256, 0, stream>>>(z_style, z_skill, Ws1, bs1, Ws2, bs2,
                                               out + (size_t)ROWS * OUTDIM);
}

// Round 3
// 7779.076 us; speedup vs baseline: 3.0135x; 2.2383x over previous
//
#include <hip/hip_runtime.h>
#include <math.h>

// Model dims
#define BATCH 128
#define DMODEL 512
#define NHEAD 8
#define NLAYER 6
#define SEQ 200
#define LATDIM 256
#define OUTDIM 6
#define DFF 2048
#define ROWS (BATCH * SEQ)   // 25600

typedef unsigned short u16;
typedef __attribute__((ext_vector_type(8))) short bfrag8;
typedef __attribute__((ext_vector_type(4))) float facc4;

__device__ __forceinline__ float gelu_f(float v) {
    return 0.5f * v * (1.0f + erff(v * 0.70710678118654752f));
}
__device__ __forceinline__ u16 f2bf(float f) {
    unsigned u = __float_as_uint(f);
    u += 0x7fffu + ((u >> 16) & 1u);
    return (u16)(u >> 16);
}

enum { MM_BIAS = 0, MM_RESID = 1, MM_GELU_BF16 = 2, MM_GELU_F32 = 3, MM_LAT = 4 };

// ---------------------------------------------------------------------------
// bf16 MFMA GEMM: C = epi(A[M,K] @ B[K,N] + bias), Bt is B transposed [N,K].
// 128x128 tile, BK=32, 4 waves each computing a 64x64 subtile via 4x4 grid of
// 16x16x32 MFMA. Fragment layouts (m89-verified):
//   A-frag: lane holds A[m=lane&15][k=quad*8+j]   (8 bf16, contiguous in K)
//   B-frag: lane holds B[k=quad*8+j][n=lane&15] = Bt[n][k] (contiguous in K)
//   C/D:    lane reg r holds D[quad*4+r][lane&15]
// LDS tiles stored [free][K] padded to 40 bf16/row (80 B: 16B-aligned rows,
// ~2-way bank aliasing only, which is free).
// ---------------------------------------------------------------------------
__global__ __launch_bounds__(256) void mm_kernel(
    const u16* __restrict__ A, const u16* __restrict__ Bt,
    const float* __restrict__ bias, float* __restrict__ Cf, u16* __restrict__ Cb,
    int M, int N, int K, int mode)
{
    __shared__ u16 As[128][40];
    __shared__ u16 Bs[128][40];
    const int tid = threadIdx.x;
    const int row0 = blockIdx.y * 128, col0 = blockIdx.x * 128;
    const int lane = tid & 63, w = tid >> 6;
    const int m_w = (w & 1) << 6, n_w = (w >> 1) << 6;
    const int l16 = lane & 15, quad = lane >> 4;
    const int srow = tid >> 1, shalf = tid & 1;

    const u16* Ap = A + (size_t)(row0 + srow) * K + shalf * 16;
    const u16* Bp = Bt + (size_t)(col0 + srow) * K + shalf * 16;

    facc4 acc[4][4] = {};

    for (int k0 = 0; k0 < K; k0 += 32) {
        uint4 a0 = *(const uint4*)(Ap + k0);
        uint4 a1 = *(const uint4*)(Ap + k0 + 8);
        uint4 b0 = *(const uint4*)(Bp + k0);
        uint4 b1 = *(const uint4*)(Bp + k0 + 8);
        __syncthreads();
        *(uint4*)&As[srow][shalf * 16]     = a0;
        *(uint4*)&As[srow][shalf * 16 + 8] = a1;
        *(uint4*)&Bs[srow][shalf * 16]     = b0;
        *(uint4*)&Bs[srow][shalf * 16 + 8] = b1;
        __syncthreads();
        bfrag8 af[4], bf[4];
        #pragma unroll
        for (int i = 0; i < 4; ++i)
            af[i] = *(const bfrag8*)&As[m_w + i * 16 + l16][quad * 8];
        #pragma unroll
        for (int j = 0; j < 4; ++j)
            bf[j] = *(const bfrag8*)&Bs[n_w + j * 16 + l16][quad * 8];
        #pragma unroll
        for (int i = 0; i < 4; ++i)
            #pragma unroll
            for (int j = 0; j < 4; ++j)
                acc[i][j] = __builtin_amdgcn_mfma_f32_16x16x32_bf16(
                    af[i], bf[j], acc[i][j], 0, 0, 0);
    }

    #pragma unroll
    for (int i = 0; i < 4; ++i) {
        #pragma unroll
        for (int r = 0; r < 4; ++r) {
            const int row = row0 + m_w + i * 16 + quad * 4 + r;
            #pragma unroll
            for (int j = 0; j < 4; ++j) {
                const int col = col0 + n_w + j * 16 + l16;
                float v = acc[i][j][r] + bias[col];
                const size_t idx = (size_t)row * N + col;
                if (mode == MM_BIAS) {
                    Cf[idx] = v;
                } else if (mode == MM_RESID) {
                    Cf[idx] += v;
                } else if (mode == MM_GELU_BF16) {
                    Cb[idx] = f2bf(gelu_f(v));
                } else if (mode == MM_GELU_F32) {
                    Cf[idx] = gelu_f(v);
                } else { // MM_LAT: gelu + positional encoding, dual output
                    v = gelu_f(v);
                    const int s = col >> 9, d = col & 511;
                    const float ang = (float)s *
                        expf((float)(d & ~1) * (-9.2103403719761836f / 512.0f));
                    v += (d & 1) ? cosf(ang) : sinf(ang);
                    Cf[idx] = v;
                    Cb[idx] = f2bf(v);
                }
            }
        }
    }
}

// ---------------------------------------------------------------------------
// Transpose-convert: W [K,N] fp32 -> Wt [N,K] bf16, 64x64 LDS tiles.
// ---------------------------------------------------------------------------
__device__ __forceinline__ void tconv_body(const float* __restrict__ W,
                                           u16* __restrict__ O, int K, int N)
{
    __shared__ u16 T[64][80];
    const int n0 = blockIdx.x * 64, k0 = blockIdx.y * 64, t = threadIdx.x;
    {
        const int kr = t >> 2, seg = t & 3;
        const float* wp = W + (size_t)(k0 + kr) * N + n0 + seg * 16;
        alignas(16) u16 tmp[16];
        #pragma unroll
        for (int q = 0; q < 4; ++q) {
            float4 f = ((const float4*)wp)[q];
            tmp[q * 4 + 0] = f2bf(f.x); tmp[q * 4 + 1] = f2bf(f.y);
            tmp[q * 4 + 2] = f2bf(f.z); tmp[q * 4 + 3] = f2bf(f.w);
        }
        *(uint4*)&T[kr][seg * 16]     = *(uint4*)&tmp[0];
        *(uint4*)&T[kr][seg * 16 + 8] = *(uint4*)&tmp[8];
    }
    __syncthreads();
    {
        const int n = t >> 2, kseg = t & 3;
        alignas(16) u16 o[16];
        #pragma unroll
        for (int i = 0; i < 16; ++i) o[i] = T[kseg * 16 + i][n];
        uint4* op = (uint4*)(O + (size_t)(n0 + n) * K + k0 + kseg * 16);
        op[0] = *(uint4*)&o[0];
        op[1] = *(uint4*)&o[8];
    }
}

__global__ __launch_bounds__(256) void tconv_kernel(
    const float* __restrict__ W, u16* __restrict__ O, int K, int N)
{
    tconv_body(W, O, K, N);
}

// QKVO batch: z = layer*4 + matrix, all 512x512
__global__ __launch_bounds__(256) void tconv4_kernel(
    const float* __restrict__ Wq, const float* __restrict__ Wk,
    const float* __restrict__ Wv, const float* __restrict__ Wo,
    u16* __restrict__ Out)
{
    const int z = blockIdx.z, layer = z >> 2, m = z & 3;
    const float* W = (m == 0 ? Wq : m == 1 ? Wk : m == 2 ? Wv : Wo)
                     + (size_t)layer * 262144;
    tconv_body(W, Out + (size_t)z * 262144, 512, 512);
}

// ---------------------------------------------------------------------------
// Fused attention, one block per (b,h), fp32 q/k/v in, bf16 ctx out.
// ---------------------------------------------------------------------------
__global__ __launch_bounds__(256) void attn_kernel(
    const float* __restrict__ q, const float* __restrict__ k,
    const float* __restrict__ v, const float* __restrict__ tb,
    u16* __restrict__ ctxb)
{
    const int h = blockIdx.x, b = blockIdx.y;
    const int tid = threadIdx.x;
    const int w = tid >> 6, lane = tid & 63;

    __shared__ float Ks[64][65];
    __shared__ float sbuf[4][200][9];
    __shared__ float qT[4][64][8];
    __shared__ float pT[4][64][8];

    const size_t bhq = (size_t)b * SEQ * DMODEL + h * 64;

    for (int ci = 0; ci < 7; ++ci) {
        const int i_base = ci * 32 + w * 8;
        const bool active = (i_base < SEQ);

        if (active) {
            #pragma unroll
            for (int qi = 0; qi < 8; ++qi)
                qT[w][lane][qi] = q[bhq + (size_t)(i_base + qi) * DMODEL + lane];
        }

        for (int t = 0; t < 4; ++t) {
            const int j0 = t * 64;
            const int jn = (SEQ - j0 < 64) ? (SEQ - j0) : 64;
            __syncthreads();
            for (int g = tid; g < jn * 16; g += 256) {
                const int row = g >> 4, c4 = (g & 15) << 2;
                float4 kv = *(const float4*)(k + bhq + (size_t)(j0 + row) * DMODEL + c4);
                Ks[row][c4 + 0] = kv.x; Ks[row][c4 + 1] = kv.y;
                Ks[row][c4 + 2] = kv.z; Ks[row][c4 + 3] = kv.w;
            }
            __syncthreads();
            if (active && lane < jn) {
                float acc[8] = {};
                #pragma unroll 8
                for (int d = 0; d < 64; ++d) {
                    const float kv = Ks[lane][d];
                    const float4 qa = *(const float4*)&qT[w][d][0];
                    const float4 qb = *(const float4*)&qT[w][d][4];
                    acc[0] = fmaf(kv, qa.x, acc[0]); acc[1] = fmaf(kv, qa.y, acc[1]);
                    acc[2] = fmaf(kv, qa.z, acc[2]); acc[3] = fmaf(kv, qa.w, acc[3]);
                    acc[4] = fmaf(kv, qb.x, acc[4]); acc[5] = fmaf(kv, qb.y, acc[5]);
                    acc[6] = fmaf(kv, qb.z, acc[6]); acc[7] = fmaf(kv, qb.w, acc[7]);
                }
                const int j = j0 + lane;
                #pragma unroll
                for (int qi = 0; qi < 8; ++qi) {
                    const float bias = tb[((h * SEQ) + i_base + qi) * SEQ + j];
                    sbuf[w][j][qi] = acc[qi] * 0.125f + bias;
                }
            }
        }

        float cacc[8] = {};
        if (active) {
            float sv[8][4];
            #pragma unroll
            for (int jj = 0; jj < 4; ++jj) {
                const int j = jj * 64 + lane;
                #pragma unroll
                for (int qi = 0; qi < 8; ++qi)
                    sv[qi][jj] = (j < SEQ) ? sbuf[w][j][qi] : -INFINITY;
            }
            #pragma unroll
            for (int qi = 0; qi < 8; ++qi) {
                float m = fmaxf(fmaxf(sv[qi][0], sv[qi][1]), fmaxf(sv[qi][2], sv[qi][3]));
                #pragma unroll
                for (int off = 32; off > 0; off >>= 1)
                    m = fmaxf(m, __shfl_xor(m, off, 64));
                float e[4], s = 0.f;
                #pragma unroll
                for (int jj = 0; jj < 4; ++jj) { e[jj] = __expf(sv[qi][jj] - m); s += e[jj]; }
                #pragma unroll
                for (int off = 32; off > 0; off >>= 1)
                    s += __shfl_xor(s, off, 64);
                const float inv = 1.0f / s;
                #pragma unroll
                for (int jj = 0; jj < 4; ++jj) {
                    const int j = jj * 64 + lane;
                    if (j < SEQ) sbuf[w][j][qi] = e[jj] * inv;
                }
            }
        }

        for (int t = 0; t < 4; ++t) {
            const int j0 = t * 64;
            const int jn = (SEQ - j0 < 64) ? (SEQ - j0) : 64;
            __syncthreads();
            for (int g = tid; g < jn * 16; g += 256) {
                const int row = g >> 4, c4 = (g & 15) << 2;
                float4 vv = *(const float4*)(v + bhq + (size_t)(j0 + row) * DMODEL + c4);
                Ks[row][c4 + 0] = vv.x; Ks[row][c4 + 1] = vv.y;
                Ks[row][c4 + 2] = vv.z; Ks[row][c4 + 3] = vv.w;
            }
            __syncthreads();
            if (active) {
                if (lane < jn) {
                    #pragma unroll
                    for (int qi = 0; qi < 8; ++qi)
                        pT[w][lane][qi] = sbuf[w][j0 + lane][qi];
                }
                for (int jj = 0; jj < jn; ++jj) {
                    const float vv = Ks[jj][lane];
                    const float4 pa = *(const float4*)&pT[w][jj][0];
                    const float4 pb = *(const float4*)&pT[w][jj][4];
                    cacc[0] = fmaf(vv, pa.x, cacc[0]); cacc[1] = fmaf(vv, pa.y, cacc[1]);
                    cacc[2] = fmaf(vv, pa.z, cacc[2]); cacc[3] = fmaf(vv, pa.w, cacc[3]);
                    cacc[4] = fmaf(vv, pb.x, cacc[4]); cacc[5] = fmaf(vv, pb.y, cacc[5]);
                    cacc[6] = fmaf(vv, pb.z, cacc[6]); cacc[7] = fmaf(vv, pb.w, cacc[7]);
                }
            }
        }

        if (active) {
            #pragma unroll
            for (int qi = 0; qi < 8; ++qi)
                ctxb[bhq + (size_t)(i_base + qi) * DMODEL + lane] = f2bf(cacc[qi]);
        }
    }
}

// In-place LayerNorm, also emits bf16 copy
__global__ __launch_bounds__(256) void ln_kernel(
    float* __restrict__ x, const float* __restrict__ g,
    const float* __restrict__ bb, u16* __restrict__ xb)
{
    const int tid = threadIdx.x;
    float* xr = x + (size_t)blockIdx.x * DMODEL;
    u16* xbr = xb + (size_t)blockIdx.x * DMODEL;
    float v0 = xr[tid], v1 = xr[tid + 256];
    __shared__ float red[256];
    red[tid] = v0 + v1;
    __syncthreads();
    for (int s = 128; s > 0; s >>= 1) { if (tid < s) red[tid] += red[tid + s]; __syncthreads(); }
    const float mu = red[0] * (1.0f / 512.0f);
    __syncthreads();
    const float d0 = v0 - mu, d1 = v1 - mu;
    red[tid] = d0 * d0 + d1 * d1;
    __syncthreads();
    for (int s = 128; s > 0; s >>= 1) { if (tid < s) red[tid] += red[tid + s]; __syncthreads(); }
    const float rstd = rsqrtf(red[0] * (1.0f / 512.0f) + 1e-5f);
    const float o0 = d0 * rstd * g[tid] + bb[tid];
    const float o1 = d1 * rstd * g[tid + 256] + bb[tid + 256];
    xr[tid] = o0; xr[tid + 256] = o1;
    xbr[tid] = f2bf(o0); xbr[tid + 256] = f2bf(o1);
}

__global__ __launch_bounds__(256) void concat_z_kernel(
    const float* __restrict__ zs, const float* __restrict__ zk, u16* __restrict__ z)
{
    const int b = blockIdx.x, t = threadIdx.x;
    z[b * 256 + t] = f2bf((t < 128) ? zs[b * 128 + t] : zk[b * 128 + t - 128]);
}

__global__ __launch_bounds__(64) void traj_head_kernel(
    const float* __restrict__ t1, const float* __restrict__ Wp2,
    const float* __restrict__ bp2, float* __restrict__ out)
{
    const int r = blockIdx.x, t = threadIdx.x;
    __shared__ float red[6][64];
    float p[6] = {};
    const float* tr = t1 + (size_t)r * 256;
    for (int kk = t; kk < 256; kk += 64) {
        float tv = tr[kk];
        #pragma unroll
        for (int c = 0; c < 6; ++c) p[c] = fmaf(tv, Wp2[kk * 6 + c], p[c]);
    }
    #pragma unroll
    for (int c = 0; c < 6; ++c) red[c][t] = p[c];
    __syncthreads();
    if (t < 6) {
        float a = 0.f;
        for (int j = 0; j < 64; ++j) a += red[t][j];
        out[(size_t)r * 6 + t] = a + bp2[t];
    }
}

__global__ __launch_bounds__(256) void sig_head_kernel(
    const float* __restrict__ zs, const float* __restrict__ zk,
    const float* __restrict__ Ws1, const float* __restrict__ bs1,
    const float* __restrict__ Ws2, const float* __restrict__ bs2,
    float* __restrict__ out)
{
    const int b = blockIdx.x, t = threadIdx.x;
    __shared__ float zrow[256];
    __shared__ float h1[256];
    zrow[t] = (t < 128) ? zs[b * 128 + t] : zk[b * 128 + t - 128];
    __syncthreads();
    float acc = bs1[t];
    for (int kk = 0; kk < 256; ++kk) acc = fmaf(zrow[kk], Ws1[kk * 256 + t], acc);
    h1[t] = gelu_f(acc);
    __syncthreads();
    if (t < 5) {
        float a = bs2[t];
        for (int kk = 0; kk < 256; ++kk) a = fmaf(h1[kk], Ws2[kk * 5 + t], a);
        out[b * 5 + t] = a;
    }
}

extern "C" void kernel_launch(void* const* d_in, const int* in_sizes, int n_in,
                              void* d_out, int out_size, void* d_ws, size_t ws_size,
                              hipStream_t stream) {
    const float* z_style   = (const float*)d_in[0];
    const float* z_skill   = (const float*)d_in[1];
    const float* W_lat     = (const float*)d_in[2];
    const float* b_lat     = (const float*)d_in[3];
    const float* temp_bias = (const float*)d_in[4];
    const float* Wq  = (const float*)d_in[5];
    const float* bq  = (const float*)d_in[6];
    const float* Wk  = (const float*)d_in[7];
    const float* bk  = (const float*)d_in[8];
    const float* Wv  = (const float*)d_in[9];
    const float* bv  = (const float*)d_in[10];
    const float* Wo  = (const float*)d_in[11];
    const float* bo  = (const float*)d_in[12];
    const float* g1  = (const float*)d_in[13];
    const float* be1 = (const float*)d_in[14];
    const float* g2  = (const float*)d_in[15];
    const float* be2 = (const float*)d_in[16];
    const float* W1  = (const float*)d_in[17];
    const float* bf1 = (const float*)d_in[18];
    const float* W2  = (const float*)d_in[19];
    const float* bf2 = (const float*)d_in[20];
    const float* Wp1 = (const float*)d_in[21];
    const float* bp1 = (const float*)d_in[22];
    const float* Wp2 = (const float*)d_in[23];
    const float* bp2 = (const float*)d_in[24];
    const float* Ws1 = (const float*)d_in[25];
    const float* bs1 = (const float*)d_in[26];
    const float* Ws2 = (const float*)d_in[27];
    const float* bs2 = (const float*)d_in[28];
    float* out = (float*)d_out;

    // ---- workspace layout (bytes) ----
    char* Wb = (char*)d_ws;
    float* x    = (float*)(Wb + 0);            // [25600,512] fp32, residual master
    float* qb   = (float*)(Wb + 52428800);     // q fp32 / ff1b(part) / t1
    float* kb   = (float*)(Wb + 104857600);    // k fp32 / ff1b(part)
    float* vb   = (float*)(Wb + 157286400);    // v fp32 / W_lat_t
    u16*  xb    = (u16*)(Wb + 209715200);      // x bf16 copy, doubles as ctxb
    u16*  qkvoT = (u16*)(Wb + 235929600);      // 24 x [512,512] bf16
    u16*  w1T   = (u16*)(Wb + 248512512);      // [2048,512] bf16 (per-layer)
    u16*  w2T   = (u16*)(Wb + 250609664);      // [512,2048] bf16 (per-layer)
    u16*  wp1T  = (u16*)(Wb + 252706816);      // [256,512] bf16
    u16*  zbb   = (u16*)(Wb + 252968960);      // [128,256] bf16
    u16*  wlatT = (u16*)vb;                    // [102400,256] bf16 (pre-layer0)
    u16*  ff1b  = (u16*)qb;                    // [25600,2048] bf16 (spans q+k)
    u16*  ctxb  = xb;
    float* t1   = qb;

    // ---- weight conversion (runs every launch; inputs restored each call) ----
    tconv4_kernel<<<dim3(8, 8, 24), 256, 0, stream>>>(Wq, Wk, Wv, Wo, qkvoT);
    tconv_kernel<<<dim3(1600, 4), 256, 0, stream>>>(W_lat, wlatT, LATDIM, DMODEL * SEQ);
    tconv_kernel<<<dim3(4, 8), 256, 0, stream>>>(Wp1, wp1T, DMODEL, 256);

    concat_z_kernel<<<BATCH, 256, 0, stream>>>(z_style, z_skill, zbb);

    // x = gelu(z @ W_lat + b_lat) + pe  (dual fp32/bf16 out)
    mm_kernel<<<dim3(800, 1), 256, 0, stream>>>(
        zbb, wlatT, b_lat, x, xb, BATCH, DMODEL * SEQ, LATDIM, MM_LAT);

    const dim3 gSq(4, 200), gFF1(16, 200), gFF2(4, 200);
    for (int l = 0; l < NLAYER; ++l) {
        // per-layer FF weight conversion
        tconv_kernel<<<dim3(32, 8), 256, 0, stream>>>(
            W1 + (size_t)l * DMODEL * DFF, w1T, DMODEL, DFF);
        tconv_kernel<<<dim3(8, 32), 256, 0, stream>>>(
            W2 + (size_t)l * DFF * DMODEL, w2T, DFF, DMODEL);

        const u16* WqT = qkvoT + (size_t)(l * 4 + 0) * 262144;
        const u16* WkT = qkvoT + (size_t)(l * 4 + 1) * 262144;
        const u16* WvT = qkvoT + (size_t)(l * 4 + 2) * 262144;
        const u16* WoT = qkvoT + (size_t)(l * 4 + 3) * 262144;

        mm_kernel<<<gSq, 256, 0, stream>>>(xb, WqT, bq + l * DMODEL, qb, nullptr,
                                           ROWS, DMODEL, DMODEL, MM_BIAS);
        mm_kernel<<<gSq, 256, 0, stream>>>(xb, WkT, bk + l * DMODEL, kb, nullptr,
                                           ROWS, DMODEL, DMODEL, MM_BIAS);
        mm_kernel<<<gSq, 256, 0, stream>>>(xb, WvT, bv + l * DMODEL, vb, nullptr,
                                           ROWS, DMODEL, DMODEL, MM_BIAS);
        attn_kernel<<<dim3(NHEAD, BATCH), 256, 0, stream>>>(qb, kb, vb, temp_bias, ctxb);
        mm_kernel<<<gSq, 256, 0, stream>>>(ctxb, WoT, bo + l * DMODEL, x, nullptr,
                                           ROWS, DMODEL, DMODEL, MM_RESID);
        ln_kernel<<<ROWS, 256, 0, stream>>>(x, g1 + l * DMODEL, be1 + l * DMODEL, xb);
        mm_kernel<<<gFF1, 256, 0, stream>>>(xb, w1T, bf1 + l * DFF, nullptr, ff1b,
                                            ROWS, DFF, DMODEL, MM_GELU_BF16);
        mm_kernel<<<gFF2, 256, 0, stream>>>(ff1b, w2T, bf2 + l * DMODEL, x, nullptr,
                                            ROWS, DMODEL, DFF, MM_RESID);
        ln_kernel<<<ROWS, 256, 0, stream>>>(x, g2 + l * DMODEL, be2 + l * DMODEL, xb);
    }

    // trajectory head
    mm_kernel<<<dim3(2, 200), 256, 0, stream>>>(xb, wp1T, bp1, t1, nullptr,
                                                ROWS, 256, DMODEL, MM_GELU_F32);
    traj_head_kernel<<<ROWS, 64, 0, stream>>>(t1, Wp2, bp2, out);

    sig_head_kernel<<<BATCH, 256, 0, stream>>>(z_style, z_skill, Ws1, bs1, Ws2, bs2,
                                               out + (size_t)ROWS * OUTDIM);
}

// Round 5
// 5323.504 us; speedup vs baseline: 4.4035x; 1.4613x over previous
//
#include <hip/hip_runtime.h>
#include <math.h>

#define BATCH 128
#define DMODEL 512
#define NHEAD 8
#define NLAYER 6
#define SEQ 200
#define LATDIM 256
#define OUTDIM 6
#define DFF 2048
#define ROWS (BATCH * SEQ)   // 25600
#define QKVS 1536            // fused qkv row stride
#define VTS 264              // Vt row stride (u16): 528B = 33*16B, bank-rotating

typedef unsigned short u16;
typedef __attribute__((ext_vector_type(8))) short bfrag8;
typedef __attribute__((ext_vector_type(4))) float facc4;

__device__ __forceinline__ float gelu_f(float v) {
    return 0.5f * v * (1.0f + erff(v * 0.70710678118654752f));
}
__device__ __forceinline__ u16 f2bf(float f) {
    unsigned u = __float_as_uint(f);
    u += 0x7fffu + ((u >> 16) & 1u);
    return (u16)(u >> 16);
}
// async global->LDS, 16B per lane; HW dest = wave-uniform base + lane*16
__device__ __forceinline__ void gl_lds16(const u16* g, u16* l) {
    __builtin_amdgcn_global_load_lds(
        (const __attribute__((address_space(1))) void*)(uintptr_t)g,
        (__attribute__((address_space(3))) void*)(uintptr_t)l,
        16, 0, 0);
}

enum { MM_QKV = 0, MM_RESID = 1, MM_GELU_BF16 = 2, MM_GELU_F32 = 3, MM_LAT = 4 };

// ---------------------------------------------------------------------------
// bf16 MFMA GEMM, m97-style: global_load_lds(16B) staging, unpadded LDS
// [128][32] tiles, 128x128 tile, BK=32, 4 waves x 64x64 subtile.
// A-frag: A[m=l16][k=quad*8+j]; B-frag: Bt[n=l16][k=quad*8+j];
// C/D: D[quad*4+r][l16]  (m89-verified)
// ---------------------------------------------------------------------------
__global__ __launch_bounds__(256) void mm_kernel(
    const u16* __restrict__ A, const u16* __restrict__ Bt,
    const float* __restrict__ bias, float* __restrict__ Cf, u16* __restrict__ Cb,
    int M, int N, int K, int mode)
{
    __shared__ __align__(16) u16 As[128 * 32];
    __shared__ __align__(16) u16 Bs[128 * 32];
    const int tid = threadIdx.x;
    const int row0 = blockIdx.y * 128, col0 = blockIdx.x * 128;
    const int lane = tid & 63, w = tid >> 6;
    const int m_w = (w & 1) << 6, n_w = (w >> 1) << 6;
    const int l16 = lane & 15, quad = lane >> 4;

    // chunk c (16B) -> row c>>2, seg c&3; thread covers chunks tid and tid+256
    const int c0 = tid, c1 = tid + 256;
    const u16* Ag0 = A + (size_t)(row0 + (c0 >> 2)) * K + (c0 & 3) * 8;
    const u16* Ag1 = A + (size_t)(row0 + (c1 >> 2)) * K + (c1 & 3) * 8;
    const u16* Bg0 = Bt + (size_t)(col0 + (c0 >> 2)) * K + (c0 & 3) * 8;
    const u16* Bg1 = Bt + (size_t)(col0 + (c1 >> 2)) * K + (c1 & 3) * 8;
    u16* Al0 = As + w * 512;            // wave-uniform LDS bases
    u16* Al1 = As + 2048 + w * 512;
    u16* Bl0 = Bs + w * 512;
    u16* Bl1 = Bs + 2048 + w * 512;

    facc4 acc[4][4] = {};

    for (int k0 = 0; k0 < K; k0 += 32) {
        __syncthreads();                 // prev iter's LDS reads done
        gl_lds16(Ag0 + k0, Al0);
        gl_lds16(Ag1 + k0, Al1);
        gl_lds16(Bg0 + k0, Bl0);
        gl_lds16(Bg1 + k0, Bl1);
        __syncthreads();                 // drains vmcnt; data visible
        bfrag8 af[4], bf[4];
        #pragma unroll
        for (int i = 0; i < 4; ++i)
            af[i] = *(const bfrag8*)&As[(m_w + i * 16 + l16) * 32 + quad * 8];
        #pragma unroll
        for (int j = 0; j < 4; ++j)
            bf[j] = *(const bfrag8*)&Bs[(n_w + j * 16 + l16) * 32 + quad * 8];
        #pragma unroll
        for (int i = 0; i < 4; ++i)
            #pragma unroll
            for (int j = 0; j < 4; ++j)
                acc[i][j] = __builtin_amdgcn_mfma_f32_16x16x32_bf16(
                    af[i], bf[j], acc[i][j], 0, 0, 0);
    }

    #pragma unroll
    for (int i = 0; i < 4; ++i) {
        #pragma unroll
        for (int r = 0; r < 4; ++r) {
            const int row = row0 + m_w + i * 16 + quad * 4 + r;
            #pragma unroll
            for (int j = 0; j < 4; ++j) {
                const int col = col0 + n_w + j * 16 + l16;
                float v = acc[i][j][r] + bias[col];
                const size_t idx = (size_t)row * N + col;
                if (mode == MM_QKV) {
                    Cb[idx] = f2bf(v);
                } else if (mode == MM_RESID) {
                    Cf[idx] += v;
                } else if (mode == MM_GELU_BF16) {
                    Cb[idx] = f2bf(gelu_f(v));
                } else if (mode == MM_GELU_F32) {
                    Cf[idx] = gelu_f(v);
                } else { // MM_LAT
                    v = gelu_f(v);
                    const int s = col >> 9, d = col & 511;
                    const float ang = (float)s *
                        expf((float)(d & ~1) * (-9.2103403719761836f / 512.0f));
                    v += (d & 1) ? cosf(ang) : sinf(ang);
                    Cf[idx] = v;
                    Cb[idx] = f2bf(v);
                }
            }
        }
    }
}

// ---------------------------------------------------------------------------
// MFMA attention. Grid (qtile=4, h=8, b=128); 4 waves; wave = 16 queries.
// qkv bf16 [25600][1536]: q cols 0.., k 512.., v 1024..
// K phase: kv = Ks[208][64], dims permuted per row: seg_pos holds dims
//   (seg_pos ^ (key&7))*8 (placed by DMA source permutation) -> conflict-free
//   b128 reads at position (dimseg ^ (key&7)).
// V phase: kv = Vt[64][VTS=264], col = key (no swizzle; stride rotates banks).
// ---------------------------------------------------------------------------
__global__ __launch_bounds__(256) void attn_kernel(
    const u16* __restrict__ qkv, const float* __restrict__ tb,
    u16* __restrict__ ctxb)
{
    const int qt = blockIdx.x, h = blockIdx.y, b = blockIdx.z;
    const int tid = threadIdx.x;
    const int w = tid >> 6, lane = tid & 63;
    const int l16 = lane & 15, quad = lane >> 4;

    __shared__ __align__(16) u16 kv[16896];        // Ks[208][64] / Vt[64][264]
    __shared__ __align__(16) u16 Ps[4][16][232];   // softmaxed P per wave

    const size_t rowbase = (size_t)b * SEQ;
    const int q0w = qt * 64 + w * 16;

    // stage K slice: 208 rows x 8 chunks = 1664 chunks, 26 wave-groups.
    // chunk c -> row key=c>>3, position seg=c&7 holds dims ((seg^(key&7))*8..)
    for (int g = w; g < 26; g += 4) {
        const int c = g * 64 + lane;
        const int key = c >> 3, seg = c & 7;
        const int krow = key < 200 ? key : 199;    // clamp: finite, discarded
        gl_lds16(qkv + (rowbase + krow) * QKVS + 512 + h * 64 +
                 ((seg ^ (key & 7)) << 3),
                 kv + g * 512);
    }
    // Q A-frags straight from global (row-clamped for tail)
    int qrow = (int)rowbase + q0w + l16;
    if (qrow > ROWS - 1) qrow = ROWS - 1;
    const u16* qp = qkv + (size_t)qrow * QKVS + h * 64 + quad * 8;
    bfrag8 aq0 = *(const bfrag8*)(qp);
    bfrag8 aq1 = *(const bfrag8*)(qp + 32);
    __syncthreads();

    // scores: 13 key-tiles of 16
    facc4 sc[13];
    #pragma unroll
    for (int nt = 0; nt < 13; ++nt) {
        const int key = nt * 16 + l16, kk = key & 7;
        bfrag8 b0 = *(const bfrag8*)&kv[key * 64 + ((quad ^ kk) << 3)];
        bfrag8 b1 = *(const bfrag8*)&kv[key * 64 + (((4 + quad) ^ kk) << 3)];
        facc4 a = {};
        a = __builtin_amdgcn_mfma_f32_16x16x32_bf16(aq0, b0, a, 0, 0, 0);
        a = __builtin_amdgcn_mfma_f32_16x16x32_bf16(aq1, b1, a, 0, 0, 0);
        sc[nt] = a;
    }
    __syncthreads();   // Ks reads done; kv reusable as Vt

    // stage V transposed: Vt[dk][VTS], col = key, zero keys >= 200
    for (int c = 0; c < 7; ++c) {
        const int key = c * 32 + (tid & 31);
        const int dkb = (tid >> 5) * 8;
        u16 vals[8];
        if (key < 200) {
            *(uint4*)vals = *(const uint4*)(qkv + (rowbase + key) * QKVS +
                                            1024 + h * 64 + dkb);
        } else {
            #pragma unroll
            for (int i = 0; i < 8; ++i) vals[i] = 0;
        }
        #pragma unroll
        for (int i = 0; i < 8; ++i)
            kv[(dkb + i) * VTS + key] = vals[i];
    }

    // softmax (in-register; row = quad*4+r, keys across l16 lanes x 13 regs)
    #pragma unroll
    for (int r = 0; r < 4; ++r) {
        const int i = q0w + quad * 4 + r;
        #pragma unroll
        for (int nt = 0; nt < 13; ++nt) {
            const int j = nt * 16 + l16;
            float s;
            if (j < 200) {
                const float tbv = (i < 200) ? tb[(h * 200 + i) * 200 + j] : 0.f;
                s = sc[nt][r] * 0.125f + tbv;
            } else s = -INFINITY;
            sc[nt][r] = s;
        }
        float m = sc[0][r];
        #pragma unroll
        for (int nt = 1; nt < 13; ++nt) m = fmaxf(m, sc[nt][r]);
        #pragma unroll
        for (int off = 8; off > 0; off >>= 1) m = fmaxf(m, __shfl_xor(m, off, 64));
        float ssum = 0.f;
        #pragma unroll
        for (int nt = 0; nt < 13; ++nt) {
            const float e = __expf(sc[nt][r] - m);
            sc[nt][r] = e; ssum += e;
        }
        #pragma unroll
        for (int off = 8; off > 0; off >>= 1) ssum += __shfl_xor(ssum, off, 64);
        const float inv = 1.0f / ssum;
        #pragma unroll
        for (int nt = 0; nt < 13; ++nt)
            Ps[w][quad * 4 + r][nt * 16 + l16] = f2bf(sc[nt][r] * inv);
        Ps[w][quad * 4 + r][208 + l16] = 0;        // zero pad keys 208..223
    }
    __syncthreads();   // Vt staged by all threads

    // PV: ctx[16 x 64] = P[16 x 224] @ V[224 x 64]
    facc4 pacc[4] = {};
    for (int ks = 0; ks < 7; ++ks) {
        bfrag8 ap = *(const bfrag8*)&Ps[w][l16][ks * 32 + quad * 8];
        #pragma unroll
        for (int nt = 0; nt < 4; ++nt) {
            const int dkrow = nt * 16 + l16;
            bfrag8 bv = *(const bfrag8*)&kv[dkrow * VTS + ks * 32 + quad * 8];
            pacc[nt] = __builtin_amdgcn_mfma_f32_16x16x32_bf16(ap, bv, pacc[nt], 0, 0, 0);
        }
    }

    #pragma unroll
    for (int r = 0; r < 4; ++r) {
        const int i = q0w + quad * 4 + r;
        if (i < 200) {
            #pragma unroll
            for (int nt = 0; nt < 4; ++nt)
                ctxb[(rowbase + i) * 512 + h * 64 + nt * 16 + l16] = f2bf(pacc[nt][r]);
        }
    }
}

// ---------------------------------------------------------------------------
// Transpose-convert W [K,N] fp32 -> Wt [N,K] bf16, batched over blockIdx.z
// ---------------------------------------------------------------------------
__global__ __launch_bounds__(256) void tconv_kernel(
    const float* __restrict__ W, u16* __restrict__ O, int K, int N,
    size_t wStride, size_t oStride)
{
    __shared__ u16 T[64][80];
    const float* Wz = W + wStride * blockIdx.z;
    u16* Oz = O + oStride * blockIdx.z;
    const int n0 = blockIdx.x * 64, k0 = blockIdx.y * 64, t = threadIdx.x;
    {
        const int kr = t >> 2, seg = t & 3;
        const float* wp = Wz + (size_t)(k0 + kr) * N + n0 + seg * 16;
        alignas(16) u16 tmp[16];
        #pragma unroll
        for (int q = 0; q < 4; ++q) {
            float4 f = ((const float4*)wp)[q];
            tmp[q * 4 + 0] = f2bf(f.x); tmp[q * 4 + 1] = f2bf(f.y);
            tmp[q * 4 + 2] = f2bf(f.z); tmp[q * 4 + 3] = f2bf(f.w);
        }
        *(uint4*)&T[kr][seg * 16]     = *(uint4*)&tmp[0];
        *(uint4*)&T[kr][seg * 16 + 8] = *(uint4*)&tmp[8];
    }
    __syncthreads();
    {
        const int n = t >> 2, kseg = t & 3;
        alignas(16) u16 o[16];
        #pragma unroll
        for (int i = 0; i < 16; ++i) o[i] = T[kseg * 16 + i][n];
        uint4* op = (uint4*)(Oz + (size_t)(n0 + n) * K + k0 + kseg * 16);
        op[0] = *(uint4*)&o[0];
        op[1] = *(uint4*)&o[8];
    }
}

// qkvo batch: z = layer*4 + {q,k,v,o}, all 512x512
__global__ __launch_bounds__(256) void tconv4_kernel(
    const float* __restrict__ Wq, const float* __restrict__ Wk,
    const float* __restrict__ Wv, const float* __restrict__ Wo,
    u16* __restrict__ Out)
{
    __shared__ u16 T[64][80];
    const int z = blockIdx.z, layer = z >> 2, m = z & 3;
    const float* W = (m == 0 ? Wq : m == 1 ? Wk : m == 2 ? Wv : Wo)
                     + (size_t)layer * 262144;
    u16* O = Out + (size_t)z * 262144;
    const int n0 = blockIdx.x * 64, k0 = blockIdx.y * 64, t = threadIdx.x;
    {
        const int kr = t >> 2, seg = t & 3;
        const float* wp = W + (size_t)(k0 + kr) * 512 + n0 + seg * 16;
        alignas(16) u16 tmp[16];
        #pragma unroll
        for (int q = 0; q < 4; ++q) {
            float4 f = ((const float4*)wp)[q];
            tmp[q * 4 + 0] = f2bf(f.x); tmp[q * 4 + 1] = f2bf(f.y);
            tmp[q * 4 + 2] = f2bf(f.z); tmp[q * 4 + 3] = f2bf(f.w);
        }
        *(uint4*)&T[kr][seg * 16]     = *(uint4*)&tmp[0];
        *(uint4*)&T[kr][seg * 16 + 8] = *(uint4*)&tmp[8];
    }
    __syncthreads();
    {
        const int n = t >> 2, kseg = t & 3;
        alignas(16) u16 o[16];
        #pragma unroll
        for (int i = 0; i < 16; ++i) o[i] = T[kseg * 16 + i][n];
        uint4* op = (uint4*)(O + (size_t)(n0 + n) * 512 + k0 + kseg * 16);
        op[0] = *(uint4*)&o[0];
        op[1] = *(uint4*)&o[8];
    }
}

// concat biases: bqkv[l][1536] = [bq[l] | bk[l] | bv[l]]
__global__ __launch_bounds__(256) void bqkv_kernel(
    const float* __restrict__ bq, const float* __restrict__ bk,
    const float* __restrict__ bv, float* __restrict__ o)
{
    const int l = blockIdx.x, t = threadIdx.x;
    for (int c = t; c < 1536; c += 256) {
        float v = (c < 512) ? bq[l * 512 + c]
                : (c < 1024) ? bk[l * 512 + c - 512]
                             : bv[l * 512 + c - 1024];
        o[l * 1536 + c] = v;
    }
}

// In-place LayerNorm, fp32 master + bf16 copy
__global__ __launch_bounds__(256) void ln_kernel(
    float* __restrict__ x, const float* __restrict__ g,
    const float* __restrict__ bb, u16* __restrict__ xb)
{
    const int tid = threadIdx.x;
    float* xr = x + (size_t)blockIdx.x * DMODEL;
    u16* xbr = xb + (size_t)blockIdx.x * DMODEL;
    float v0 = xr[tid], v1 = xr[tid + 256];
    __shared__ float red[256];
    red[tid] = v0 + v1;
    __syncthreads();
    for (int s = 128; s > 0; s >>= 1) { if (tid < s) red[tid] += red[tid + s]; __syncthreads(); }
    const float mu = red[0] * (1.0f / 512.0f);
    __syncthreads();
    const float d0 = v0 - mu, d1 = v1 - mu;
    red[tid] = d0 * d0 + d1 * d1;
    __syncthreads();
    for (int s = 128; s > 0; s >>= 1) { if (tid < s) red[tid] += red[tid + s]; __syncthreads(); }
    const float rstd = rsqrtf(red[0] * (1.0f / 512.0f) + 1e-5f);
    const float o0 = d0 * rstd * g[tid] + bb[tid];
    const float o1 = d1 * rstd * g[tid + 256] + bb[tid + 256];
    xr[tid] = o0; xr[tid + 256] = o1;
    xbr[tid] = f2bf(o0); xbr[tid + 256] = f2bf(o1);
}

__global__ __launch_bounds__(256) void concat_z_kernel(
    const float* __restrict__ zs, const float* __restrict__ zk, u16* __restrict__ z)
{
    const int b = blockIdx.x, t = threadIdx.x;
    z[b * 256 + t] = f2bf((t < 128) ? zs[b * 128 + t] : zk[b * 128 + t - 128]);
}

__global__ __launch_bounds__(64) void traj_head_kernel(
    const float* __restrict__ t1, const float* __restrict__ Wp2,
    const float* __restrict__ bp2, float* __restrict__ out)
{
    const int r = blockIdx.x, t = threadIdx.x;
    __shared__ float red[6][64];
    float p[6] = {};
    const float* tr = t1 + (size_t)r * 256;
    for (int kk = t; kk < 256; kk += 64) {
        float tv = tr[kk];
        #pragma unroll
        for (int c = 0; c < 6; ++c) p[c] = fmaf(tv, Wp2[kk * 6 + c], p[c]);
    }
    #pragma unroll
    for (int c = 0; c < 6; ++c) red[c][t] = p[c];
    __syncthreads();
    if (t < 6) {
        float a = 0.f;
        for (int j = 0; j < 64; ++j) a += red[t][j];
        out[(size_t)r * 6 + t] = a + bp2[t];
    }
}

__global__ __launch_bounds__(256) void sig_head_kernel(
    const float* __restrict__ zs, const float* __restrict__ zk,
    const float* __restrict__ Ws1, const float* __restrict__ bs1,
    const float* __restrict__ Ws2, const float* __restrict__ bs2,
    float* __restrict__ out)
{
    const int b = blockIdx.x, t = threadIdx.x;
    __shared__ float zrow[256];
    __shared__ float h1[256];
    zrow[t] = (t < 128) ? zs[b * 128 + t] : zk[b * 128 + t - 128];
    __syncthreads();
    float acc = bs1[t];
    for (int kk = 0; kk < 256; ++kk) acc = fmaf(zrow[kk], Ws1[kk * 256 + t], acc);
    h1[t] = gelu_f(acc);
    __syncthreads();
    if (t < 5) {
        float a = bs2[t];
        for (int kk = 0; kk < 256; ++kk) a = fmaf(h1[kk], Ws2[kk * 5 + t], a);
        out[b * 5 + t] = a;
    }
}

extern "C" void kernel_launch(void* const* d_in, const int* in_sizes, int n_in,
                              void* d_out, int out_size, void* d_ws, size_t ws_size,
                              hipStream_t stream) {
    const float* z_style   = (const float*)d_in[0];
    const float* z_skill   = (const float*)d_in[1];
    const float* W_lat     = (const float*)d_in[2];
    const float* b_lat     = (const float*)d_in[3];
    const float* temp_bias = (const float*)d_in[4];
    const float* Wq  = (const float*)d_in[5];
    const float* bq  = (const float*)d_in[6];
    const float* Wk  = (const float*)d_in[7];
    const float* bk  = (const float*)d_in[8];
    const float* Wv  = (const float*)d_in[9];
    const float* bv  = (const float*)d_in[10];
    const float* Wo  = (const float*)d_in[11];
    const float* bo  = (const float*)d_in[12];
    const float* g1  = (const float*)d_in[13];
    const float* be1 = (const float*)d_in[14];
    const float* g2  = (const float*)d_in[15];
    const float* be2 = (const float*)d_in[16];
    const float* W1  = (const float*)d_in[17];
    const float* bf1 = (const float*)d_in[18];
    const float* W2  = (const float*)d_in[19];
    const float* bf2 = (const float*)d_in[20];
    const float* Wp1 = (const float*)d_in[21];
    const float* bp1 = (const float*)d_in[22];
    const float* Wp2 = (const float*)d_in[23];
    const float* bp2 = (const float*)d_in[24];
    const float* Ws1 = (const float*)d_in[25];
    const float* bs1 = (const float*)d_in[26];
    const float* Ws2 = (const float*)d_in[27];
    const float* bs2 = (const float*)d_in[28];
    float* out = (float*)d_out;

    // ---- workspace layout (bytes), total ~221.6 MB ----
    char* Wb = (char*)d_ws;
    float* x     = (float*)(Wb + 0);             // [25600,512] fp32 residual
    u16*  xb     = (u16*)(Wb + 52428800);        // [25600,512] bf16 (LN out)
    u16*  qkv    = (u16*)(Wb + 78643200);        // [25600,1536] bf16
    u16*  cx     = (u16*)(Wb + 157286400);       // ctx bf16 [25600,512]
    u16*  ff1b   = (u16*)(Wb + 78643200);        // [25600,2048] overlays qkv+cx
    u16*  wlatT  = (u16*)(Wb + 78643200);        // [102400,256] pre-loop only
    float* t1    = (float*)(Wb + 157286400);     // head scratch (cx dead)
    u16*  qkvoT  = (u16*)(Wb + 183500800);       // 24 x [512,512]
    u16*  w1T    = (u16*)(Wb + 196083712);       // 6 x [2048,512]
    u16*  w2T    = (u16*)(Wb + 208666624);       // 6 x [512,2048]
    u16*  wp1T   = (u16*)(Wb + 221249536);       // [256,512]
    float* bqkv  = (float*)(Wb + 221511680);     // [6,1536]
    u16*  zbb    = (u16*)(Wb + 221548544);       // [128,256]

    // ---- weight conversion (every launch; inputs restored each call) ----
    tconv4_kernel<<<dim3(8, 8, 24), 256, 0, stream>>>(Wq, Wk, Wv, Wo, qkvoT);
    tconv_kernel<<<dim3(32, 8, 6), 256, 0, stream>>>(W1, w1T, DMODEL, DFF,
                                                     (size_t)DMODEL * DFF, (size_t)DMODEL * DFF);
    tconv_kernel<<<dim3(8, 32, 6), 256, 0, stream>>>(W2, w2T, DFF, DMODEL,
                                                     (size_t)DMODEL * DFF, (size_t)DMODEL * DFF);
    tconv_kernel<<<dim3(1600, 4, 1), 256, 0, stream>>>(W_lat, wlatT, LATDIM, DMODEL * SEQ, 0, 0);
    tconv_kernel<<<dim3(4, 8, 1), 256, 0, stream>>>(Wp1, wp1T, DMODEL, 256, 0, 0);
    bqkv_kernel<<<NLAYER, 256, 0, stream>>>(bq, bk, bv, bqkv);
    concat_z_kernel<<<BATCH, 256, 0, stream>>>(z_style, z_skill, zbb);

    // x = gelu(z @ W_lat + b_lat) + pe  (dual fp32/bf16)
    mm_kernel<<<dim3(800, 1), 256, 0, stream>>>(
        zbb, wlatT, b_lat, x, xb, BATCH, DMODEL * SEQ, LATDIM, MM_LAT);

    for (int l = 0; l < NLAYER; ++l) {
        mm_kernel<<<dim3(12, 200), 256, 0, stream>>>(
            xb, qkvoT + (size_t)l * 4 * 262144, bqkv + l * 1536, nullptr, qkv,
            ROWS, QKVS, DMODEL, MM_QKV);
        attn_kernel<<<dim3(4, NHEAD, BATCH), 256, 0, stream>>>(qkv, temp_bias, cx);
        mm_kernel<<<dim3(4, 200), 256, 0, stream>>>(
            cx, qkvoT + (size_t)(l * 4 + 3) * 262144, bo + l * DMODEL, x, nullptr,
            ROWS, DMODEL, DMODEL, MM_RESID);
        ln_kernel<<<ROWS, 256, 0, stream>>>(x, g1 + l * DMODEL, be1 + l * DMODEL, xb);
        mm_kernel<<<dim3(16, 200), 256, 0, stream>>>(
            xb, w1T + (size_t)l * DMODEL * DFF, bf1 + l * DFF, nullptr, ff1b,
            ROWS, DFF, DMODEL, MM_GELU_BF16);
        mm_kernel<<<dim3(4, 200), 256, 0, stream>>>(
            ff1b, w2T + (size_t)l * DMODEL * DFF, bf2 + l * DMODEL, x, nullptr,
            ROWS, DMODEL, DFF, MM_RESID);
        ln_kernel<<<ROWS, 256, 0, stream>>>(x, g2 + l * DMODEL, be2 + l * DMODEL, xb);
    }

    // heads
    mm_kernel<<<dim3(2, 200), 256, 0, stream>>>(
        xb, wp1T, bp1, t1, nullptr, ROWS, 256, DMODEL, MM_GELU_F32);
    traj_head_kernel<<<ROWS, 64, 0, stream>>>(t1, Wp2, bp2, out);
    sig_head_kernel<<<BATCH, 256, 0, stream>>>(z_style, z_skill, Ws1, bs1, Ws2, bs2,
                                               out + (size_t)ROWS * OUTDIM);
}

// Round 6
// 4213.958 us; speedup vs baseline: 5.5630x; 1.2633x over previous
//
#include <hip/hip_runtime.h>
#include <math.h>

#define BATCH 128
#define DMODEL 512
#define NHEAD 8
#define NLAYER 6
#define SEQ 200
#define LATDIM 256
#define OUTDIM 6
#define DFF 2048
#define ROWS (BATCH * SEQ)   // 25600
#define QKVS 1536            // fused qkv row stride
#define VTS 264              // Vt row stride (u16): 528B, bank-rotating

typedef unsigned short u16;
typedef __attribute__((ext_vector_type(8))) short bfrag8;
typedef __attribute__((ext_vector_type(4))) float facc4;

__device__ __forceinline__ float gelu_f(float v) {
    return 0.5f * v * (1.0f + erff(v * 0.70710678118654752f));
}
__device__ __forceinline__ u16 f2bf(float f) {
    unsigned u = __float_as_uint(f);
    u += 0x7fffu + ((u >> 16) & 1u);
    return (u16)(u >> 16);
}
// async global->LDS, 16B per lane; HW dest = wave-uniform base + lane*16
__device__ __forceinline__ void gl_lds16(const u16* g, u16* l) {
    __builtin_amdgcn_global_load_lds(
        (const __attribute__((address_space(1))) void*)(uintptr_t)g,
        (__attribute__((address_space(3))) void*)(uintptr_t)l,
        16, 0, 0);
}

enum { MM_QKV = 0, MM_RESID = 1, MM_GELU_BF16 = 2, MM_GELU_F32 = 3, MM_LAT = 4 };

// ---------------------------------------------------------------------------
// bf16 MFMA GEMM: double-buffered global_load_lds staging (1 barrier/iter),
// conflict-free LDS via DMA source chunk permutation.
// 128x128 tile, BK=32, 4 waves x 64x64 subtile of 16x16x32 MFMA.
// LDS chunk p (16B) holds global chunk ((p&3)^((p>>3)&3)) of row p>>2;
// frag read position = quad ^ ((l16>>1)&3)  -> max 2 lanes/bank-group (free).
// ---------------------------------------------------------------------------
__global__ __launch_bounds__(256) void mm_kernel(
    const u16* __restrict__ A, const u16* __restrict__ Bt,
    const float* __restrict__ bias, float* __restrict__ Cf, u16* __restrict__ Cb,
    const float* __restrict__ pe, int M, int N, int K, int mode)
{
    __shared__ __align__(16) u16 As[2 * 4096];
    __shared__ __align__(16) u16 Bs[2 * 4096];
    const int tid = threadIdx.x;
    const int row0 = blockIdx.y * 128, col0 = blockIdx.x * 128;
    const int lane = tid & 63, w = tid >> 6;
    const int m_w = (w & 1) << 6, n_w = (w >> 1) << 6;
    const int l16 = lane & 15, quad = lane >> 4;

    // staging source (chunk-permuted): this thread feeds LDS chunks tid, tid+256
    const int r0 = tid >> 2;
    const int seg = ((tid & 3) ^ ((tid >> 3) & 3)) << 3;   // permuted k-chunk, elems
    const u16* Ag0 = A + (size_t)(row0 + r0) * K + seg;
    const u16* Ag1 = A + (size_t)(row0 + r0 + 64) * K + seg;
    const u16* Bg0 = Bt + (size_t)(col0 + r0) * K + seg;
    const u16* Bg1 = Bt + (size_t)(col0 + r0 + 64) * K + seg;

    const int pos = (quad ^ ((l16 >> 1) & 3)) << 3;        // frag read chunk, elems

    facc4 acc[4][4] = {};
    const int iters = K >> 5;
    int cur = 0;

    {   // prologue: stage k-chunk 0 into buffer 0
        u16* Ald = As + w * 512;
        u16* Bld = Bs + w * 512;
        gl_lds16(Ag0, Ald);
        gl_lds16(Ag1, Ald + 2048);
        gl_lds16(Bg0, Bld);
        gl_lds16(Bg1, Bld + 2048);
    }

    for (int it = 0; it < iters; ++it) {
        __syncthreads();          // drains current buffer's DMA (vmcnt) + prior reads
        if (it + 1 < iters) {     // prefetch next tile into other buffer (no wait)
            const int nb = (cur ^ 1) * 4096;
            const int ko = (it + 1) << 5;
            u16* Ald = As + nb + w * 512;
            u16* Bld = Bs + nb + w * 512;
            gl_lds16(Ag0 + ko, Ald);
            gl_lds16(Ag1 + ko, Ald + 2048);
            gl_lds16(Bg0 + ko, Bld);
            gl_lds16(Bg1 + ko, Bld + 2048);
        }
        const u16* Ab = As + cur * 4096;
        const u16* Bb = Bs + cur * 4096;
        bfrag8 af[4], bf[4];
        #pragma unroll
        for (int i = 0; i < 4; ++i)
            af[i] = *(const bfrag8*)&Ab[(m_w + i * 16 + l16) * 32 + pos];
        #pragma unroll
        for (int j = 0; j < 4; ++j)
            bf[j] = *(const bfrag8*)&Bb[(n_w + j * 16 + l16) * 32 + pos];
        #pragma unroll
        for (int i = 0; i < 4; ++i)
            #pragma unroll
            for (int j = 0; j < 4; ++j)
                acc[i][j] = __builtin_amdgcn_mfma_f32_16x16x32_bf16(
                    af[i], bf[j], acc[i][j], 0, 0, 0);
        cur ^= 1;
    }

    #pragma unroll
    for (int i = 0; i < 4; ++i) {
        #pragma unroll
        for (int r = 0; r < 4; ++r) {
            const int row = row0 + m_w + i * 16 + quad * 4 + r;
            #pragma unroll
            for (int j = 0; j < 4; ++j) {
                const int col = col0 + n_w + j * 16 + l16;
                float v = acc[i][j][r] + bias[col];
                const size_t idx = (size_t)row * N + col;
                if (mode == MM_QKV) {
                    Cb[idx] = f2bf(v);
                } else if (mode == MM_RESID) {
                    Cf[idx] += v;
                } else if (mode == MM_GELU_BF16) {
                    Cb[idx] = f2bf(gelu_f(v));
                } else if (mode == MM_GELU_F32) {
                    Cf[idx] = gelu_f(v);
                } else { // MM_LAT: gelu + precomputed positional encoding, dual out
                    v = gelu_f(v) + pe[col];
                    Cf[idx] = v;
                    Cb[idx] = f2bf(v);
                }
            }
        }
    }
}

// positional encoding table pe[s*512+d], 102400 entries
__global__ __launch_bounds__(256) void pe_kernel(float* __restrict__ pe)
{
    const int idx = blockIdx.x * 256 + threadIdx.x;
    const int s = idx >> 9, d = idx & 511;
    const float ang = (float)s * expf((float)(d & ~1) * (-9.2103403719761836f / 512.0f));
    pe[idx] = (d & 1) ? cosf(ang) : sinf(ang);
}

// ---------------------------------------------------------------------------
// MFMA attention. Grid (qtile=4, h=8, b=128); 4 waves; wave = 16 queries.
// ---------------------------------------------------------------------------
__global__ __launch_bounds__(256) void attn_kernel(
    const u16* __restrict__ qkv, const float* __restrict__ tb,
    u16* __restrict__ ctxb)
{
    const int qt = blockIdx.x, h = blockIdx.y, b = blockIdx.z;
    const int tid = threadIdx.x;
    const int w = tid >> 6, lane = tid & 63;
    const int l16 = lane & 15, quad = lane >> 4;

    __shared__ __align__(16) u16 kv[16896];        // Ks[208][64] / Vt[64][264]
    __shared__ __align__(16) u16 Ps[4][16][232];   // softmaxed P per wave

    const size_t rowbase = (size_t)b * SEQ;
    const int q0w = qt * 64 + w * 16;

    // stage K slice: 208 rows x 8 chunks; chunk position seg holds dims
    // ((seg^(key&7))*8..) via DMA source permutation -> conflict-free reads
    for (int g = w; g < 26; g += 4) {
        const int c = g * 64 + lane;
        const int key = c >> 3, seg = c & 7;
        const int krow = key < 200 ? key : 199;
        gl_lds16(qkv + (rowbase + krow) * QKVS + 512 + h * 64 +
                 ((seg ^ (key & 7)) << 3),
                 kv + g * 512);
    }
    int qrow = (int)rowbase + q0w + l16;
    if (qrow > ROWS - 1) qrow = ROWS - 1;
    const u16* qp = qkv + (size_t)qrow * QKVS + h * 64 + quad * 8;
    bfrag8 aq0 = *(const bfrag8*)(qp);
    bfrag8 aq1 = *(const bfrag8*)(qp + 32);
    __syncthreads();

    facc4 sc[13];
    #pragma unroll
    for (int nt = 0; nt < 13; ++nt) {
        const int key = nt * 16 + l16, kk = key & 7;
        bfrag8 b0 = *(const bfrag8*)&kv[key * 64 + ((quad ^ kk) << 3)];
        bfrag8 b1 = *(const bfrag8*)&kv[key * 64 + (((4 + quad) ^ kk) << 3)];
        facc4 a = {};
        a = __builtin_amdgcn_mfma_f32_16x16x32_bf16(aq0, b0, a, 0, 0, 0);
        a = __builtin_amdgcn_mfma_f32_16x16x32_bf16(aq1, b1, a, 0, 0, 0);
        sc[nt] = a;
    }
    __syncthreads();

    // stage V transposed: Vt[dk][VTS], col = key, zero keys >= 200
    for (int c = 0; c < 7; ++c) {
        const int key = c * 32 + (tid & 31);
        const int dkb = (tid >> 5) * 8;
        u16 vals[8];
        if (key < 200) {
            *(uint4*)vals = *(const uint4*)(qkv + (rowbase + key) * QKVS +
                                            1024 + h * 64 + dkb);
        } else {
            #pragma unroll
            for (int i = 0; i < 8; ++i) vals[i] = 0;
        }
        #pragma unroll
        for (int i = 0; i < 8; ++i)
            kv[(dkb + i) * VTS + key] = vals[i];
    }

    #pragma unroll
    for (int r = 0; r < 4; ++r) {
        const int i = q0w + quad * 4 + r;
        #pragma unroll
        for (int nt = 0; nt < 13; ++nt) {
            const int j = nt * 16 + l16;
            float s;
            if (j < 200) {
                const float tbv = (i < 200) ? tb[(h * 200 + i) * 200 + j] : 0.f;
                s = sc[nt][r] * 0.125f + tbv;
            } else s = -INFINITY;
            sc[nt][r] = s;
        }
        float m = sc[0][r];
        #pragma unroll
        for (int nt = 1; nt < 13; ++nt) m = fmaxf(m, sc[nt][r]);
        #pragma unroll
        for (int off = 8; off > 0; off >>= 1) m = fmaxf(m, __shfl_xor(m, off, 64));
        float ssum = 0.f;
        #pragma unroll
        for (int nt = 0; nt < 13; ++nt) {
            const float e = __expf(sc[nt][r] - m);
            sc[nt][r] = e; ssum += e;
        }
        #pragma unroll
        for (int off = 8; off > 0; off >>= 1) ssum += __shfl_xor(ssum, off, 64);
        const float inv = 1.0f / ssum;
        #pragma unroll
        for (int nt = 0; nt < 13; ++nt)
            Ps[w][quad * 4 + r][nt * 16 + l16] = f2bf(sc[nt][r] * inv);
        Ps[w][quad * 4 + r][208 + l16] = 0;
    }
    __syncthreads();

    facc4 pacc[4] = {};
    for (int ks = 0; ks < 7; ++ks) {
        bfrag8 ap = *(const bfrag8*)&Ps[w][l16][ks * 32 + quad * 8];
        #pragma unroll
        for (int nt = 0; nt < 4; ++nt) {
            const int dkrow = nt * 16 + l16;
            bfrag8 bv = *(const bfrag8*)&kv[dkrow * VTS + ks * 32 + quad * 8];
            pacc[nt] = __builtin_amdgcn_mfma_f32_16x16x32_bf16(ap, bv, pacc[nt], 0, 0, 0);
        }
    }

    #pragma unroll
    for (int r = 0; r < 4; ++r) {
        const int i = q0w + quad * 4 + r;
        if (i < 200) {
            #pragma unroll
            for (int nt = 0; nt < 4; ++nt)
                ctxb[(rowbase + i) * 512 + h * 64 + nt * 16 + l16] = f2bf(pacc[nt][r]);
        }
    }
}

// ---------------------------------------------------------------------------
// Transpose-convert W [K,N] fp32 -> Wt [N,K] bf16, batched over blockIdx.z
// ---------------------------------------------------------------------------
__global__ __launch_bounds__(256) void tconv_kernel(
    const float* __restrict__ W, u16* __restrict__ O, int K, int N,
    size_t wStride, size_t oStride)
{
    __shared__ u16 T[64][80];
    const float* Wz = W + wStride * blockIdx.z;
    u16* Oz = O + oStride * blockIdx.z;
    const int n0 = blockIdx.x * 64, k0 = blockIdx.y * 64, t = threadIdx.x;
    {
        const int kr = t >> 2, seg = t & 3;
        const float* wp = Wz + (size_t)(k0 + kr) * N + n0 + seg * 16;
        alignas(16) u16 tmp[16];
        #pragma unroll
        for (int q = 0; q < 4; ++q) {
            float4 f = ((const float4*)wp)[q];
            tmp[q * 4 + 0] = f2bf(f.x); tmp[q * 4 + 1] = f2bf(f.y);
            tmp[q * 4 + 2] = f2bf(f.z); tmp[q * 4 + 3] = f2bf(f.w);
        }
        *(uint4*)&T[kr][seg * 16]     = *(uint4*)&tmp[0];
        *(uint4*)&T[kr][seg * 16 + 8] = *(uint4*)&tmp[8];
    }
    __syncthreads();
    {
        const int n = t >> 2, kseg = t & 3;
        alignas(16) u16 o[16];
        #pragma unroll
        for (int i = 0; i < 16; ++i) o[i] = T[kseg * 16 + i][n];
        uint4* op = (uint4*)(Oz + (size_t)(n0 + n) * K + k0 + kseg * 16);
        op[0] = *(uint4*)&o[0];
        op[1] = *(uint4*)&o[8];
    }
}

// qkvo batch: z = layer*4 + {q,k,v,o}, all 512x512
__global__ __launch_bounds__(256) void tconv4_kernel(
    const float* __restrict__ Wq, const float* __restrict__ Wk,
    const float* __restrict__ Wv, const float* __restrict__ Wo,
    u16* __restrict__ Out)
{
    __shared__ u16 T[64][80];
    const int z = blockIdx.z, layer = z >> 2, m = z & 3;
    const float* W = (m == 0 ? Wq : m == 1 ? Wk : m == 2 ? Wv : Wo)
                     + (size_t)layer * 262144;
    u16* O = Out + (size_t)z * 262144;
    const int n0 = blockIdx.x * 64, k0 = blockIdx.y * 64, t = threadIdx.x;
    {
        const int kr = t >> 2, seg = t & 3;
        const float* wp = W + (size_t)(k0 + kr) * 512 + n0 + seg * 16;
        alignas(16) u16 tmp[16];
        #pragma unroll
        for (int q = 0; q < 4; ++q) {
            float4 f = ((const float4*)wp)[q];
            tmp[q * 4 + 0] = f2bf(f.x); tmp[q * 4 + 1] = f2bf(f.y);
            tmp[q * 4 + 2] = f2bf(f.z); tmp[q * 4 + 3] = f2bf(f.w);
        }
        *(uint4*)&T[kr][seg * 16]     = *(uint4*)&tmp[0];
        *(uint4*)&T[kr][seg * 16 + 8] = *(uint4*)&tmp[8];
    }
    __syncthreads();
    {
        const int n = t >> 2, kseg = t & 3;
        alignas(16) u16 o[16];
        #pragma unroll
        for (int i = 0; i < 16; ++i) o[i] = T[kseg * 16 + i][n];
        uint4* op = (uint4*)(O + (size_t)(n0 + n) * 512 + k0 + kseg * 16);
        op[0] = *(uint4*)&o[0];
        op[1] = *(uint4*)&o[8];
    }
}

// concat biases: bqkv[l][1536] = [bq[l] | bk[l] | bv[l]]
__global__ __launch_bounds__(256) void bqkv_kernel(
    const float* __restrict__ bq, const float* __restrict__ bk,
    const float* __restrict__ bv, float* __restrict__ o)
{
    const int l = blockIdx.x, t = threadIdx.x;
    for (int c = t; c < 1536; c += 256) {
        float v = (c < 512) ? bq[l * 512 + c]
                : (c < 1024) ? bk[l * 512 + c - 512]
                             : bv[l * 512 + c - 1024];
        o[l * 1536 + c] = v;
    }
}

// LayerNorm: 1 wave per row, 4 rows/block, vectorized, shuffle-only reduce
__global__ __launch_bounds__(256) void ln_kernel(
    float* __restrict__ x, const float* __restrict__ g,
    const float* __restrict__ bb, u16* __restrict__ xb)
{
    const int w = threadIdx.x >> 6, lane = threadIdx.x & 63;
    const size_t row = (size_t)blockIdx.x * 4 + w;
    float* xr = x + row * DMODEL;
    u16* xbr = xb + row * DMODEL;
    const int c = lane * 8;
    float4 a = *(const float4*)(xr + c);
    float4 b = *(const float4*)(xr + c + 4);
    float s = a.x + a.y + a.z + a.w + b.x + b.y + b.z + b.w;
    #pragma unroll
    for (int off = 32; off > 0; off >>= 1) s += __shfl_xor(s, off, 64);
    const float mu = s * (1.0f / 512.0f);
    a.x -= mu; a.y -= mu; a.z -= mu; a.w -= mu;
    b.x -= mu; b.y -= mu; b.z -= mu; b.w -= mu;
    float v = a.x * a.x + a.y * a.y + a.z * a.z + a.w * a.w
            + b.x * b.x + b.y * b.y + b.z * b.z + b.w * b.w;
    #pragma unroll
    for (int off = 32; off > 0; off >>= 1) v += __shfl_xor(v, off, 64);
    const float rstd = rsqrtf(v * (1.0f / 512.0f) + 1e-5f);
    float4 g0 = *(const float4*)(g + c), g1 = *(const float4*)(g + c + 4);
    float4 b0 = *(const float4*)(bb + c), b1 = *(const float4*)(bb + c + 4);
    float4 o0, o1;
    o0.x = a.x * rstd * g0.x + b0.x; o0.y = a.y * rstd * g0.y + b0.y;
    o0.z = a.z * rstd * g0.z + b0.z; o0.w = a.w * rstd * g0.w + b0.w;
    o1.x = b.x * rstd * g1.x + b1.x; o1.y = b.y * rstd * g1.y + b1.y;
    o1.z = b.z * rstd * g1.z + b1.z; o1.w = b.w * rstd * g1.w + b1.w;
    *(float4*)(xr + c) = o0;
    *(float4*)(xr + c + 4) = o1;
    alignas(16) u16 ob[8] = { f2bf(o0.x), f2bf(o0.y), f2bf(o0.z), f2bf(o0.w),
                              f2bf(o1.x), f2bf(o1.y), f2bf(o1.z), f2bf(o1.w) };
    *(uint4*)(xbr + c) = *(uint4*)ob;
}

__global__ __launch_bounds__(256) void concat_z_kernel(
    const float* __restrict__ zs, const float* __restrict__ zk, u16* __restrict__ z)
{
    const int b = blockIdx.x, t = threadIdx.x;
    z[b * 256 + t] = f2bf((t < 128) ? zs[b * 128 + t] : zk[b * 128 + t - 128]);
}

__global__ __launch_bounds__(64) void traj_head_kernel(
    const float* __restrict__ t1, const float* __restrict__ Wp2,
    const float* __restrict__ bp2, float* __restrict__ out)
{
    const int r = blockIdx.x, t = threadIdx.x;
    __shared__ float red[6][64];
    float p[6] = {};
    const float* tr = t1 + (size_t)r * 256;
    for (int kk = t; kk < 256; kk += 64) {
        float tv = tr[kk];
        #pragma unroll
        for (int c = 0; c < 6; ++c) p[c] = fmaf(tv, Wp2[kk * 6 + c], p[c]);
    }
    #pragma unroll
    for (int c = 0; c < 6; ++c) red[c][t] = p[c];
    __syncthreads();
    if (t < 6) {
        float a = 0.f;
        for (int j = 0; j < 64; ++j) a += red[t][j];
        out[(size_t)r * 6 + t] = a + bp2[t];
    }
}

__global__ __launch_bounds__(256) void sig_head_kernel(
    const float* __restrict__ zs, const float* __restrict__ zk,
    const float* __restrict__ Ws1, const float* __restrict__ bs1,
    const float* __restrict__ Ws2, const float* __restrict__ bs2,
    float* __restrict__ out)
{
    const int b = blockIdx.x, t = threadIdx.x;
    __shared__ float zrow[256];
    __shared__ float h1[256];
    zrow[t] = (t < 128) ? zs[b * 128 + t] : zk[b * 128 + t - 128];
    __syncthreads();
    float acc = bs1[t];
    for (int kk = 0; kk < 256; ++kk) acc = fmaf(zrow[kk], Ws1[kk * 256 + t], acc);
    h1[t] = gelu_f(acc);
    __syncthreads();
    if (t < 5) {
        float a = bs2[t];
        for (int kk = 0; kk < 256; ++kk) a = fmaf(h1[kk], Ws2[kk * 5 + t], a);
        out[b * 5 + t] = a;
    }
}

extern "C" void kernel_launch(void* const* d_in, const int* in_sizes, int n_in,
                              void* d_out, int out_size, void* d_ws, size_t ws_size,
                              hipStream_t stream) {
    const float* z_style   = (const float*)d_in[0];
    const float* z_skill   = (const float*)d_in[1];
    const float* W_lat     = (const float*)d_in[2];
    const float* b_lat     = (const float*)d_in[3];
    const float* temp_bias = (const float*)d_in[4];
    const float* Wq  = (const float*)d_in[5];
    const float* bq  = (const float*)d_in[6];
    const float* Wk  = (const float*)d_in[7];
    const float* bk  = (const float*)d_in[8];
    const float* Wv  = (const float*)d_in[9];
    const float* bv  = (const float*)d_in[10];
    const float* Wo  = (const float*)d_in[11];
    const float* bo  = (const float*)d_in[12];
    const float* g1  = (const float*)d_in[13];
    const float* be1 = (const float*)d_in[14];
    const float* g2  = (const float*)d_in[15];
    const float* be2 = (const float*)d_in[16];
    const float* W1  = (const float*)d_in[17];
    const float* bf1 = (const float*)d_in[18];
    const float* W2  = (const float*)d_in[19];
    const float* bf2 = (const float*)d_in[20];
    const float* Wp1 = (const float*)d_in[21];
    const float* bp1 = (const float*)d_in[22];
    const float* Wp2 = (const float*)d_in[23];
    const float* bp2 = (const float*)d_in[24];
    const float* Ws1 = (const float*)d_in[25];
    const float* bs1 = (const float*)d_in[26];
    const float* Ws2 = (const float*)d_in[27];
    const float* bs2 = (const float*)d_in[28];
    float* out = (float*)d_out;

    // ---- workspace layout (bytes), total ~222.1 MB ----
    char* Wb = (char*)d_ws;
    float* x     = (float*)(Wb + 0);             // [25600,512] fp32 residual
    u16*  xb     = (u16*)(Wb + 52428800);        // [25600,512] bf16 (LN out)
    u16*  qkv    = (u16*)(Wb + 78643200);        // [25600,1536] bf16
    u16*  cx     = (u16*)(Wb + 157286400);       // ctx bf16 [25600,512]
    u16*  ff1b   = (u16*)(Wb + 78643200);        // [25600,2048] overlays qkv+cx
    u16*  wlatT  = (u16*)(Wb + 78643200);        // [102400,256] pre-loop only
    float* t1    = (float*)(Wb + 157286400);     // head scratch (cx dead)
    u16*  qkvoT  = (u16*)(Wb + 183500800);       // 24 x [512,512]
    u16*  w1T    = (u16*)(Wb + 196083712);       // 6 x [2048,512]
    u16*  w2T    = (u16*)(Wb + 208666624);       // 6 x [512,2048]
    u16*  wp1T   = (u16*)(Wb + 221249536);       // [256,512]
    float* bqkv  = (float*)(Wb + 221511680);     // [6,1536]
    u16*  zbb    = (u16*)(Wb + 221548544);       // [128,256]
    float* pe    = (float*)(Wb + 221614080);     // [102400] fp32 PE table

    // ---- weight conversion (every launch; inputs restored each call) ----
    tconv4_kernel<<<dim3(8, 8, 24), 256, 0, stream>>>(Wq, Wk, Wv, Wo, qkvoT);
    tconv_kernel<<<dim3(32, 8, 6), 256, 0, stream>>>(W1, w1T, DMODEL, DFF,
                                                     (size_t)DMODEL * DFF, (size_t)DMODEL * DFF);
    tconv_kernel<<<dim3(8, 32, 6), 256, 0, stream>>>(W2, w2T, DFF, DMODEL,
                                                     (size_t)DMODEL * DFF, (size_t)DMODEL * DFF);
    tconv_kernel<<<dim3(1600, 4, 1), 256, 0, stream>>>(W_lat, wlatT, LATDIM, DMODEL * SEQ, 0, 0);
    tconv_kernel<<<dim3(4, 8, 1), 256, 0, stream>>>(Wp1, wp1T, DMODEL, 256, 0, 0);
    bqkv_kernel<<<NLAYER, 256, 0, stream>>>(bq, bk, bv, bqkv);
    concat_z_kernel<<<BATCH, 256, 0, stream>>>(z_style, z_skill, zbb);
    pe_kernel<<<400, 256, 0, stream>>>(pe);

    // x = gelu(z @ W_lat + b_lat) + pe  (dual fp32/bf16)
    mm_kernel<<<dim3(800, 1), 256, 0, stream>>>(
        zbb, wlatT, b_lat, x, xb, pe, BATCH, DMODEL * SEQ, LATDIM, MM_LAT);

    for (int l = 0; l < NLAYER; ++l) {
        mm_kernel<<<dim3(12, 200), 256, 0, stream>>>(
            xb, qkvoT + (size_t)l * 4 * 262144, bqkv + l * 1536, nullptr, qkv, pe,
            ROWS, QKVS, DMODEL, MM_QKV);
        attn_kernel<<<dim3(4, NHEAD, BATCH), 256, 0, stream>>>(qkv, temp_bias, cx);
        mm_kernel<<<dim3(4, 200), 256, 0, stream>>>(
            cx, qkvoT + (size_t)(l * 4 + 3) * 262144, bo + l * DMODEL, x, nullptr, pe,
            ROWS, DMODEL, DMODEL, MM_RESID);
        ln_kernel<<<ROWS / 4, 256, 0, stream>>>(x, g1 + l * DMODEL, be1 + l * DMODEL, xb);
        mm_kernel<<<dim3(16, 200), 256, 0, stream>>>(
            xb, w1T + (size_t)l * DMODEL * DFF, bf1 + l * DFF, nullptr, ff1b, pe,
            ROWS, DFF, DMODEL, MM_GELU_BF16);
        mm_kernel<<<dim3(4, 200), 256, 0, stream>>>(
            ff1b, w2T + (size_t)l * DMODEL * DFF, bf2 + l * DMODEL, x, nullptr, pe,
            ROWS, DMODEL, DFF, MM_RESID);
        ln_kernel<<<ROWS / 4, 256, 0, stream>>>(x, g2 + l * DMODEL, be2 + l * DMODEL, xb);
    }

    // heads
    mm_kernel<<<dim3(2, 200), 256, 0, stream>>>(
        xb, wp1T, bp1, t1, nullptr, pe, ROWS, 256, DMODEL, MM_GELU_F32);
    traj_head_kernel<<<ROWS, 64, 0, stream>>>(t1, Wp2, bp2, out);
    sig_head_kernel<<<BATCH, 256, 0, stream>>>(z_style, z_skill, Ws1, bs1, Ws2, bs2,
                                               out + (size_t)ROWS * OUTDIM);
}